// Round 3
// baseline (5798.023 us; speedup 1.0000x reference)
//
#include <hip/hip_runtime.h>
#include <hip/hip_cooperative_groups.h>

namespace cg = cooperative_groups;

typedef unsigned int u32;
typedef unsigned long long u64;

#define CH_ 128
#define TAIL_M 4096u
#define MAX_ROUNDS 4000

__device__ __forceinline__ u32 f2ord(float f){
  u32 u = __float_as_uint(f);
  return ((int)u < 0) ? ~u : (u | 0x80000000u);
}
__device__ __forceinline__ float ord2f(u32 u){
  return (u & 0x80000000u) ? __uint_as_float(u & 0x7FFFFFFFu) : __uint_as_float(~u);
}
__device__ __forceinline__ u32 ldu32(const u32* p){
  return __hip_atomic_load(p, __ATOMIC_RELAXED, __HIP_MEMORY_SCOPE_AGENT);
}
__device__ __forceinline__ u64 ldu64(const u64* p){
  return __hip_atomic_load(p, __ATOMIC_RELAXED, __HIP_MEMORY_SCOPE_AGENT);
}
__device__ __forceinline__ void stu32(u32* p, u32 v){
  __hip_atomic_store(p, v, __ATOMIC_RELAXED, __HIP_MEMORY_SCOPE_AGENT);
}
// atomicMax with cheap hi-word pre-check. Plain (possibly stale) load is
// monotonicity-safe: stale <= current, so skipping when stale_hi > k_hi is safe.
__device__ __forceinline__ void amax64(u64* a, u64 k){
  u32 hi = ((const u32*)a)[1];
  if (hi <= (u32)(k >> 32)) atomicMax((unsigned long long*)a, (unsigned long long)k);
}

// ---------------- init ----------------
__global__ void k_init(u32* hdr, u32* mxbits, double* den, u64* b0, u64* b1,
                       int* craw, int* medge, u32* dead, int N){
  int i0 = blockIdx.x*blockDim.x + threadIdx.x;
  int nt = gridDim.x*blockDim.x;
  for (int v = i0; v < N; v += nt){
    mxbits[v]=0u; den[v]=0.0; b0[v]=0ull; b1[v]=0ull;
    craw[v]=v; medge[v]=-1; dead[v]=0u;
  }
  if (i0 == 0){
    for (int i = 0; i < 16; i++) hdr[i] = 0u;
    hdr[6] = (u32)N;
  }
}

// zero hist/cur2/uniqcnt AFTER k_match (they alias the A0 region)
__global__ void k_init2(u32* hist, u32* cur2, u32* uniqcnt, int n){
  int i = blockIdx.x*blockDim.x + threadIdx.x;
  if (i < n){ hist[i]=0u; cur2[i]=0u; uniqcnt[i]=0u; }
}

// ---------------- per-node dot products: s=x.w1, t=x.w2 ----------------
__global__ void k_dots(const float* __restrict__ x, const float* __restrict__ lw,
                       float* __restrict__ s, float* __restrict__ t, int N){
  int wid = threadIdx.x >> 6, lane = threadIdx.x & 63;
  int node = blockIdx.x*4 + wid;
  if (node >= N) return;
  const float* xr = x + (size_t)node*CH_;
  float xa = xr[lane], xb = xr[64+lane];
  float sv = xa*lw[lane]      + xb*lw[64+lane];
  float tv = xa*lw[128+lane]  + xb*lw[192+lane];
  #pragma unroll
  for (int m = 1; m < 64; m <<= 1){ sv += __shfl_xor(sv, m); tv += __shfl_xor(tv, m); }
  if (lane == 0){ s[node]=sv; t[node]=tv; }
}

// ---------------- raw score + segment max over col ----------------
__global__ void k_rawmax(const float* __restrict__ s, const float* __restrict__ t,
                         const int* __restrict__ row, const int* __restrict__ col,
                         const float* __restrict__ lb, float* __restrict__ rawex,
                         u32* __restrict__ mxbits, int E){
  float b = lb[0];
  int i0 = blockIdx.x*blockDim.x + threadIdx.x;
  int nt = gridDim.x*blockDim.x;
  for (int e = i0; e < E; e += nt){
    float raw = (s[row[e]] + t[col[e]]) + b;
    rawex[e] = raw;
    atomicMax(&mxbits[col[e]], f2ord(raw));
  }
}

// ---------------- ex = exp(raw-mx), den = segsum(ex) in f64 ----------------
__global__ void k_exden(const int* __restrict__ col, const u32* __restrict__ mxbits,
                        float* __restrict__ rawex, double* __restrict__ den, int E){
  int i0 = blockIdx.x*blockDim.x + threadIdx.x;
  int nt = gridDim.x*blockDim.x;
  for (int e = i0; e < E; e += nt){
    int c = col[e];
    float ex = expf(rawex[e] - ord2f(mxbits[c]));
    rawex[e] = ex;
    atomicAdd(&den[c], (double)ex);
  }
}

// ---------------- score (in-place), packed entries, seed b0 (round 0) ----
__global__ void k_scorekey(const int* __restrict__ row, const int* __restrict__ col,
                           float* __restrict__ rawex, const double* __restrict__ den,
                           uint4* __restrict__ A0, u64* b0, int E){
  int i0 = blockIdx.x*blockDim.x + threadIdx.x;
  int nt = gridDim.x*blockDim.x;
  for (int e = i0; e < E; e += nt){
    int r = row[e], c = col[e];
    float d = (float)den[c];
    float sc = rawex[e]/d + 0.5f;          // > 0 -> float bits order-monotone
    rawex[e] = sc;                          // rawex now holds the score
    u32 sb = __float_as_uint(sc);
    A0[e] = make_uint4((u32)e, (u32)r, (u32)c, sb);
    u64 k = (1ull << 52) | ((u64)sb << 20) | (u64)(0xFFFFFu - (u32)e); // round 0 key
    amax64(b0 + r, k);
    amax64(b0 + c, k);
  }
}

// ---------------- cooperative matching: 2-phase rounds, no dependent chains ----
__global__ void __launch_bounds__(1024)
k_match(u32* hdr, u64* b0, u64* b1, int* __restrict__ craw, int* __restrict__ medge,
        u32* __restrict__ dead, uint4* A0, uint4* A1, int E){
  cg::grid_group g = cg::this_grid();
  u32* cnt = hdr + 8;
  int tid  = blockIdx.x*blockDim.x + threadIdx.x;
  int nt   = gridDim.x*blockDim.x;
  int lane = threadIdx.x & 63;
  u32 m = (u32)E;

  // ---- round 0, phase B only: A0 complete, b0 seeded (prefix 1) ----
  for (u32 i = (u32)tid; i < m; i += (u32)nt){
    uint4 en = A0[i];
    u64 k = (1ull << 52) | ((u64)en.w << 20) | (u64)(0xFFFFFu - en.x);
    if (ldu64(b0 + en.y) == k && ldu64(b0 + en.z) == k){
      craw[en.z] = (int)en.y; medge[en.y] = (int)en.x;
      stu32(dead + en.y, 1u); stu32(dead + en.z, 1u);
    }
  }
  __threadfence(); g.sync();

  int R = 1;
  // ---- grid phase ----
  while (m > TAIL_M && R < MAX_ROUNDS){
    uint4* cur = (R & 1) ? A0 : A1;          // list L_{R-1}
    uint4* nxt = (R & 1) ? A1 : A0;          // list L_R
    u64*   nb  = (R & 1) ? b1 : b0;          // best-buffer for round R
    u32* cslot = cnt + (R & 3);
    if (tid == 0) stu32(cnt + ((R+2)&3), 0u);
    u64 pfx = ((u64)(R+1)) << 52;
    // Phase A: filter dead, seed nb, wave-aggregated compaction
    for (u32 i = (u32)tid; i < m; i += (u32)nt){
      uint4 en = cur[i];
      bool alive = (ldu32(dead + en.y) | ldu32(dead + en.z)) == 0u;
      if (alive){
        u64 k = pfx | ((u64)en.w << 20) | (u64)(0xFFFFFu - en.x);
        amax64(nb + en.y, k);
        amax64(nb + en.z, k);
      }
      u64 mask = __ballot(alive);
      if (mask){
        int leader = __ffsll((unsigned long long)mask) - 1;
        u32 base = 0u;
        if (lane == leader) base = atomicAdd(cslot, (u32)__popcll(mask));
        base = (u32)__shfl((int)base, leader);
        if (alive) nxt[base + (u32)__popcll(mask & ((1ull << lane) - 1ull))] = en;
      }
    }
    __threadfence(); g.sync();
    u32 m2 = ldu32(cslot);
    // Phase B: mutual-dominance match
    for (u32 i = (u32)tid; i < m2; i += (u32)nt){
      uint4 en = nxt[i];
      u64 k = pfx | ((u64)en.w << 20) | (u64)(0xFFFFFu - en.x);
      if (ldu64(nb + en.y) == k && ldu64(nb + en.z) == k){
        craw[en.z] = (int)en.y; medge[en.y] = (int)en.x;
        stu32(dead + en.y, 1u); stu32(dead + en.z, 1u);
      }
    }
    __threadfence(); g.sync();
    m = m2; R++;
  }

  // ---- tail phase: single block ----
  if (blockIdx.x != 0) return;
  while (m != 0u && R < MAX_ROUNDS){
    uint4* cur = (R & 1) ? A0 : A1;
    uint4* nxt = (R & 1) ? A1 : A0;
    u64*   nb  = (R & 1) ? b1 : b0;
    u32* cslot = cnt + (R & 3);
    if (threadIdx.x == 0) stu32(cnt + ((R+2)&3), 0u);
    u64 pfx = ((u64)(R+1)) << 52;
    __syncthreads();
    for (u32 i = threadIdx.x; i < m; i += blockDim.x){
      uint4 en = cur[i];
      bool alive = (ldu32(dead + en.y) | ldu32(dead + en.z)) == 0u;
      if (alive){
        u64 k = pfx | ((u64)en.w << 20) | (u64)(0xFFFFFu - en.x);
        amax64(nb + en.y, k);
        amax64(nb + en.z, k);
      }
      u64 mask = __ballot(alive);
      if (mask){
        int leader = __ffsll((unsigned long long)mask) - 1;
        u32 base = 0u;
        if (lane == leader) base = atomicAdd(cslot, (u32)__popcll(mask));
        base = (u32)__shfl((int)base, leader);
        if (alive) nxt[base + (u32)__popcll(mask & ((1ull << lane) - 1ull))] = en;
      }
    }
    __threadfence(); __syncthreads();
    u32 m2 = ldu32(cslot);
    for (u32 i = threadIdx.x; i < m2; i += blockDim.x){
      uint4 en = nxt[i];
      u64 k = pfx | ((u64)en.w << 20) | (u64)(0xFFFFFu - en.x);
      if (ldu64(nb + en.y) == k && ldu64(nb + en.z) == k){
        craw[en.z] = (int)en.y; medge[en.y] = (int)en.x;
        stu32(dead + en.y, 1u); stu32(dead + en.z, 1u);
      }
    }
    __threadfence(); __syncthreads();
    m = m2; R++;
  }
}

__global__ void k_rootflag(const int* __restrict__ craw, u32* __restrict__ rf, int N){
  int i = blockIdx.x*blockDim.x + threadIdx.x;
  if (i < N) rf[i] = (craw[i] == i) ? 1u : 0u;
}

// ---------------- generic exclusive scan (n <= 65536) ----------------
__global__ void scan_p1(const u32* __restrict__ in, u32* __restrict__ out,
                        u32* __restrict__ bsums, const u32* __restrict__ nptr){
  __shared__ u32 sh[256];
  u32 n = *nptr;
  int t = threadIdx.x;
  u32 i = blockIdx.x*256u + (u32)t;
  u32 v = (i < n) ? in[i] : 0u;
  sh[t] = v; __syncthreads();
  for (int o = 1; o < 256; o <<= 1){
    u32 a = (t >= o) ? sh[t-o] : 0u;
    __syncthreads();
    sh[t] += a;
    __syncthreads();
  }
  if (i < n) out[i] = sh[t] - v;
  if (t == 255) bsums[blockIdx.x] = sh[255];
}
__global__ void scan_p2(u32* bsums, u32* total){
  __shared__ u32 sh[256];
  int t = threadIdx.x;
  u32 v = bsums[t];
  sh[t] = v; __syncthreads();
  for (int o = 1; o < 256; o <<= 1){
    u32 a = (t >= o) ? sh[t-o] : 0u;
    __syncthreads();
    sh[t] += a;
    __syncthreads();
  }
  bsums[t] = sh[t] - v;
  if (t == 255 && total) *total = sh[255];
}
__global__ void scan_p3(u32* out, const u32* __restrict__ bsums, const u32* __restrict__ nptr){
  u32 n = *nptr;
  u32 i = blockIdx.x*256u + threadIdx.x;
  if (i < n) out[i] += bsums[blockIdx.x];
}

// ---------------- final cluster ids (+ write cluster output) ----------------
__global__ void k_clusterout(const int* __restrict__ craw, const u32* __restrict__ newid,
                             int* __restrict__ clout, float* __restrict__ out,
                             size_t offC, int N){
  int i = blockIdx.x*blockDim.x + threadIdx.x;
  if (i < N){
    int cl = (int)newid[craw[i]];
    clout[i] = cl;
    out[offC + i] = (float)cl;
  }
}

__global__ void k_hist(const int* __restrict__ row, const int* __restrict__ clout,
                       u32* __restrict__ hist, int E){
  int i0 = blockIdx.x*blockDim.x + threadIdx.x;
  int nt = gridDim.x*blockDim.x;
  for (int e = i0; e < E; e += nt) atomicAdd(&hist[clout[row[e]]], 1u);
}

__global__ void k_scatter(const int* __restrict__ row, const int* __restrict__ col,
                          const int* __restrict__ clout, const u32* __restrict__ segoff,
                          u32* __restrict__ cur2, u32* __restrict__ ccbuf, int E){
  int i0 = blockIdx.x*blockDim.x + threadIdx.x;
  int nt = gridDim.x*blockDim.x;
  for (int e = i0; e < E; e += nt){
    int cr = clout[row[e]];
    u32 pos = segoff[cr] + atomicAdd(&cur2[cr], 1u);
    ccbuf[pos] = (u32)clout[col[e]];
  }
}

// ---------------- per-segment sort + dedup (1 wave / block) ----------------
__global__ void k_segsort(const u32* __restrict__ hdr, const u32* __restrict__ hist,
                          const u32* __restrict__ segoff, u32* __restrict__ ccbuf,
                          u32* __restrict__ uniqcnt){
  int c = (int)hdr[2];
  __shared__ u32 sh[1024];
  int lane = threadIdx.x;   // block = 64 threads
  for (int seg = blockIdx.x; seg < c; seg += gridDim.x){
    int n = (int)hist[seg];
    if (n <= 0){ if (lane == 0) uniqcnt[seg] = 0u; continue; }
    u32 off = segoff[seg];
    if (n <= 64){
      u32 v = (lane < n) ? ccbuf[off + lane] : 0xFFFFFFFFu;
      #pragma unroll
      for (int k = 2; k <= 64; k <<= 1)
        for (int j = k >> 1; j > 0; j >>= 1){
          u32 p = __shfl_xor(v, j);
          bool up  = ((lane & k) == 0);
          bool low = ((lane & j) == 0);
          u32 mn = v < p ? v : p, mx = v < p ? p : v;
          v = (up == low) ? mn : mx;
        }
      u32 pv = __shfl_up(v, 1);
      bool un = (lane < n) && (lane == 0 || v != pv);
      u64 bal = __ballot(un);
      int cnt = __popcll(bal);
      int rk  = __popcll(bal & ((1ull << lane) - 1ull));
      if (un) ccbuf[off + rk] = v;
      if (lane == 0) uniqcnt[seg] = (u32)cnt;
    } else {
      int nn = n > 1024 ? 1024 : n;
      for (int i = lane; i < nn; i += 64) sh[i] = ccbuf[off + i];
      __syncthreads();
      for (int p = 0; p < nn; p++){
        int st = p & 1;
        for (int i = lane; 2*i + 1 + st < nn; i += 64){
          int a = 2*i + st;
          u32 x0 = sh[a], x1 = sh[a+1];
          if (x0 > x1){ sh[a] = x1; sh[a+1] = x0; }
        }
        __syncthreads();
      }
      if (lane == 0){
        int cnt = 0; u32 prev = 0u;
        for (int i = 0; i < nn; i++){
          u32 xv = sh[i];
          if (i == 0 || xv != prev){ ccbuf[off + cnt] = xv; cnt++; prev = xv; }
        }
        uniqcnt[seg] = (u32)cnt;
      }
      __syncthreads();
    }
  }
}

// ---------------- write new_edge_index ----------------
__global__ void k_writeedges(const u32* __restrict__ hdr, const u32* __restrict__ segoff,
                             const u32* __restrict__ uniqcnt, const u32* __restrict__ uniqoff,
                             const u32* __restrict__ ccbuf, float* __restrict__ out){
  int c = (int)hdr[2]; u32 Ep = hdr[3];
  size_t base = (size_t)c * CH_;
  int gw   = (blockIdx.x*blockDim.x + threadIdx.x) >> 6;
  int lane = threadIdx.x & 63;
  int nw   = (gridDim.x*blockDim.x) >> 6;
  for (int seg = gw; seg < c; seg += nw){
    int cnt = (int)uniqcnt[seg];
    u32 so = segoff[seg], uo = uniqoff[seg];
    for (int j = lane; j < cnt; j += 64){
      u32 cc = ccbuf[so + j];
      out[base + uo + j]              = (float)seg;
      out[base + (size_t)Ep + uo + j] = (float)cc;
    }
  }
}

// ---------------- new_x / new_batch / new_edge_score (wave per root) ----------------
__global__ void k_final(const u32* __restrict__ hdr, const int* __restrict__ craw,
                        const u32* __restrict__ newid, const int* __restrict__ medge,
                        const int* __restrict__ row, const int* __restrict__ col,
                        const float* __restrict__ score, const int* __restrict__ batch,
                        const float* __restrict__ x, float* __restrict__ out, int N){
  int c = (int)hdr[2]; u32 Ep = hdr[3];
  size_t offB = (size_t)c * CH_ + 2ull * (size_t)Ep;
  size_t offS = offB + (size_t)c;
  int gw   = (blockIdx.x*blockDim.x + threadIdx.x) >> 6;
  int lane = threadIdx.x & 63;
  int nw   = (gridDim.x*blockDim.x) >> 6;
  for (int i = gw; i < N; i += nw){
    if (craw[i] != i) continue;
    int j = (int)newid[i];
    int e = medge[i];
    int lo = i, hi = i; float sc = 1.0f;
    if (e >= 0){
      int r = row[e], cc = col[e];
      lo = min(r, cc); hi = max(r, cc);
      sc = score[e];
    }
    float v0 = x[(size_t)lo*CH_ + lane];
    float v1 = x[(size_t)lo*CH_ + 64 + lane];
    if (hi != lo){ v0 += x[(size_t)hi*CH_ + lane]; v1 += x[(size_t)hi*CH_ + 64 + lane]; }
    out[(size_t)j*CH_ + lane]      = v0 * sc;
    out[(size_t)j*CH_ + 64 + lane] = v1 * sc;
    if (lane == 0){
      out[offB + j] = (float)batch[hi];  // CPU-XLA scatter: last (max-index) member wins
      out[offS + j] = sc;
    }
  }
}

extern "C" void kernel_launch(void* const* d_in, const int* in_sizes, int n_in,
                              void* d_out, int out_size, void* d_ws, size_t ws_size,
                              hipStream_t stream) {
  const float* x     = (const float*)d_in[0];
  const int*   eidx  = (const int*)d_in[1];
  const int*   batch = (const int*)d_in[2];
  const float* lw    = (const float*)d_in[3];
  const float* lb    = (const float*)d_in[4];

  int N = in_sizes[0] / CH_;
  int E = in_sizes[1] / 2;
  const int* row = eidx;
  const int* col = eidx + E;
  float* out = (float*)d_out;

  // ---- workspace carve ----
  char* w = (char*)d_ws;
  size_t off = 0;
  auto carve = [&](size_t bytes) -> void* {
    void* p = w + off;
    off += (bytes + 255) & ~(size_t)255;
    return p;
  };
  u32*    hdr    = (u32*)   carve(256);
  double* den    = (double*)carve((size_t)N*8);
  u64*    b0     = (u64*)   carve((size_t)N*8);
  u64*    b1     = (u64*)   carve((size_t)N*8);
  float*  s      = (float*) carve((size_t)N*4);
  float*  t      = (float*) carve((size_t)N*4);
  float*  rawex  = (float*) carve((size_t)E*4);   // becomes score
  u32*    mxbits = (u32*)   carve((size_t)N*4);
  int*    craw   = (int*)   carve((size_t)N*4);
  u32*    rf     = (u32*)   carve((size_t)N*4);
  u32*    newid  = (u32*)   carve((size_t)N*4);
  int*    medge  = (int*)   carve((size_t)N*4);
  int*    clout  = (int*)   carve((size_t)N*4);
  u32*    dead   = (u32*)   carve((size_t)N*4);
  uint4*  A0     = (uint4*) carve((size_t)E*16);
  uint4*  A1     = (uint4*) carve((size_t)E*16);
  u32*    bsums  = (u32*)   carve(256*4);
  // alias post-match scratch into the (then-dead) A0 region
  char* a = (char*)A0;
  size_t aoff = 0;
  auto acarve = [&](size_t bytes) -> void* {
    void* p = a + aoff;
    aoff += (bytes + 255) & ~(size_t)255;
    return p;
  };
  u32* ccbuf   = (u32*)acarve((size_t)E*4);
  u32* hist    = (u32*)acarve((size_t)(N+64)*4);
  u32* segoff  = (u32*)acarve((size_t)(N+64)*4);
  u32* cur2    = (u32*)acarve((size_t)(N+64)*4);
  u32* uniqcnt = (u32*)acarve((size_t)(N+64)*4);
  u32* uniqoff = (u32*)acarve((size_t)(N+64)*4);
  (void)ws_size; (void)n_in;

  int nbE = (E + 255) / 256;
  int nbN = (N + 255) / 256;

  k_init<<<512, 256, 0, stream>>>(hdr, mxbits, den, b0, b1, craw, medge, dead, N);
  k_dots<<<(N + 3)/4, 256, 0, stream>>>(x, lw, s, t, N);
  k_rawmax<<<nbE, 256, 0, stream>>>(s, t, row, col, lb, rawex, mxbits, E);
  k_exden<<<nbE, 256, 0, stream>>>(col, mxbits, rawex, den, E);
  k_scorekey<<<nbE, 256, 0, stream>>>(row, col, rawex, den, A0, b0, E);

  {
    int dev = 0; hipGetDevice(&dev);
    int cus = 0; hipDeviceGetAttribute(&cus, hipDeviceAttributeMultiprocessorCount, dev);
    if (cus <= 0) cus = 256;
    int nb = 0;
    hipOccupancyMaxActiveBlocksPerMultiprocessor(&nb, k_match, 1024, 0);
    if (nb <= 0) nb = 1;
    int grid = nb * cus;
    if (grid > 2048) grid = 2048;
    void* kargs[] = { &hdr, &b0, &b1, &craw, &medge, &dead, &A0, &A1, &E };
    hipLaunchCooperativeKernel((void*)k_match, dim3(grid), dim3(1024), kargs, 0, stream);
  }

  k_rootflag<<<nbN, 256, 0, stream>>>(craw, rf, N);

  // scan rootflag -> newid ; total -> hdr[2] (= c). n from hdr[6] (= N)
  scan_p1<<<256, 256, 0, stream>>>(rf, newid, bsums, &hdr[6]);
  scan_p2<<<1, 256, 0, stream>>>(bsums, &hdr[2]);
  scan_p3<<<256, 256, 0, stream>>>(newid, bsums, &hdr[6]);

  k_clusterout<<<nbN, 256, 0, stream>>>(craw, newid, clout, out, (size_t)(out_size - N), N);
  k_init2<<<(N + 64 + 255)/256, 256, 0, stream>>>(hist, cur2, uniqcnt, N + 64);
  k_hist<<<nbE, 256, 0, stream>>>(row, clout, hist, E);

  // scan hist -> segoff ; n from hdr[2] (= c)
  scan_p1<<<256, 256, 0, stream>>>(hist, segoff, bsums, &hdr[2]);
  scan_p2<<<1, 256, 0, stream>>>(bsums, &hdr[4]);
  scan_p3<<<256, 256, 0, stream>>>(segoff, bsums, &hdr[2]);

  k_scatter<<<nbE, 256, 0, stream>>>(row, col, clout, segoff, cur2, ccbuf, E);
  k_segsort<<<4096, 64, 0, stream>>>(hdr, hist, segoff, ccbuf, uniqcnt);

  // scan uniqcnt -> uniqoff ; total -> hdr[3] (= E')
  scan_p1<<<256, 256, 0, stream>>>(uniqcnt, uniqoff, bsums, &hdr[2]);
  scan_p2<<<1, 256, 0, stream>>>(bsums, &hdr[3]);
  scan_p3<<<256, 256, 0, stream>>>(uniqoff, bsums, &hdr[2]);

  k_writeedges<<<2048, 256, 0, stream>>>(hdr, segoff, uniqcnt, uniqoff, ccbuf, out);
  k_final<<<4096, 256, 0, stream>>>(hdr, craw, newid, medge, row, col, rawex, batch, x, out, N);
}

// Round 4
// 1324.817 us; speedup vs baseline: 4.3765x; 4.3765x over previous
//
#include <hip/hip_runtime.h>
#include <hip/hip_cooperative_groups.h>

namespace cg = cooperative_groups;

typedef unsigned int u32;
typedef unsigned long long u64;

#define CH_ 128
#define TAIL_M 12288u
#define MAX_ROUNDS 4000

__device__ __forceinline__ u32 f2ord(float f){
  u32 u = __float_as_uint(f);
  return ((int)u < 0) ? ~u : (u | 0x80000000u);
}
__device__ __forceinline__ float ord2f(u32 u){
  return (u & 0x80000000u) ? __uint_as_float(u & 0x7FFFFFFFu) : __uint_as_float(~u);
}
__device__ __forceinline__ u32 ldu32(const u32* p){
  return __hip_atomic_load(p, __ATOMIC_RELAXED, __HIP_MEMORY_SCOPE_AGENT);
}
__device__ __forceinline__ u64 ldu64(const u64* p){
  return __hip_atomic_load(p, __ATOMIC_RELAXED, __HIP_MEMORY_SCOPE_AGENT);
}
// atomicMax with cheap hi-word pre-check. Plain (possibly stale) load is
// monotonicity-safe: stale <= current, so skipping when stale_hi > k_hi is safe.
__device__ __forceinline__ void amax64(u64* a, u64 k){
  u32 hi = ((const u32*)a)[1];
  if (hi <= (u32)(k >> 32)) atomicMax((unsigned long long*)a, (unsigned long long)k);
}

// ---------------- init ----------------
__global__ void k_init(u32* hdr, u32* mxbits, double* den, u64* b0, u64* b1,
                       int* craw, int* medge, int N){
  int i0 = blockIdx.x*blockDim.x + threadIdx.x;
  int nt = gridDim.x*blockDim.x;
  for (int v = i0; v < N; v += nt){
    mxbits[v]=0u; den[v]=0.0; b0[v]=0ull; b1[v]=0ull; craw[v]=v; medge[v]=-1;
  }
  if (i0 == 0){
    for (int i = 0; i < 16; i++) hdr[i] = 0u;
    hdr[6] = (u32)N;
  }
}

// zero hist/cur2/uniqcnt AFTER k_match (they alias the A0 region)
__global__ void k_init2(u32* hist, u32* cur2, u32* uniqcnt, int n){
  int i = blockIdx.x*blockDim.x + threadIdx.x;
  if (i < n){ hist[i]=0u; cur2[i]=0u; uniqcnt[i]=0u; }
}

// ---------------- per-node dot products: s=x.w1, t=x.w2 ----------------
__global__ void k_dots(const float* __restrict__ x, const float* __restrict__ lw,
                       float* __restrict__ s, float* __restrict__ t, int N){
  int wid = threadIdx.x >> 6, lane = threadIdx.x & 63;
  int node = blockIdx.x*4 + wid;
  if (node >= N) return;
  const float* xr = x + (size_t)node*CH_;
  float xa = xr[lane], xb = xr[64+lane];
  float sv = xa*lw[lane]      + xb*lw[64+lane];
  float tv = xa*lw[128+lane]  + xb*lw[192+lane];
  #pragma unroll
  for (int m = 1; m < 64; m <<= 1){ sv += __shfl_xor(sv, m); tv += __shfl_xor(tv, m); }
  if (lane == 0){ s[node]=sv; t[node]=tv; }
}

// ---------------- raw score + segment max over col ----------------
__global__ void k_rawmax(const float* __restrict__ s, const float* __restrict__ t,
                         const int* __restrict__ row, const int* __restrict__ col,
                         const float* __restrict__ lb, float* __restrict__ rawex,
                         u32* __restrict__ mxbits, int E){
  float b = lb[0];
  int i0 = blockIdx.x*blockDim.x + threadIdx.x;
  int nt = gridDim.x*blockDim.x;
  for (int e = i0; e < E; e += nt){
    float raw = (s[row[e]] + t[col[e]]) + b;
    rawex[e] = raw;
    atomicMax(&mxbits[col[e]], f2ord(raw));
  }
}

// ---------------- ex = exp(raw-mx), den = segsum(ex) in f64 ----------------
__global__ void k_exden(const int* __restrict__ col, const u32* __restrict__ mxbits,
                        float* __restrict__ rawex, double* __restrict__ den, int E){
  int i0 = blockIdx.x*blockDim.x + threadIdx.x;
  int nt = gridDim.x*blockDim.x;
  for (int e = i0; e < E; e += nt){
    int c = col[e];
    float ex = expf(rawex[e] - ord2f(mxbits[c]));
    rawex[e] = ex;
    atomicAdd(&den[c], (double)ex);
  }
}

// ---------------- score (in-place), packed entries, prologue best(round 0) ----
__global__ void k_scorekey(const int* __restrict__ row, const int* __restrict__ col,
                           float* __restrict__ rawex, const double* __restrict__ den,
                           u32* __restrict__ rc, uint4* __restrict__ A0,
                           u64* b0, int E){
  int i0 = blockIdx.x*blockDim.x + threadIdx.x;
  int nt = gridDim.x*blockDim.x;
  for (int e = i0; e < E; e += nt){
    int r = row[e], c = col[e];
    float d = (float)den[c];
    float sc = rawex[e]/d + 0.5f;          // > 0 -> float bits order-monotone
    rawex[e] = sc;                          // rawex now holds the score
    u32 sb = __float_as_uint(sc);
    rc[e] = ((u32)r << 16) | (u32)c;        // N < 65536
    A0[e] = make_uint4((u32)e, (u32)r, (u32)c, sb);
    u64 k = (1ull << 52) | ((u64)sb << 20) | (u64)(0xFFFFFu - (u32)e); // round 0 key
    amax64(b0 + r, k);
    amax64(b0 + c, k);
  }
}

// ---------------- matching core ----------------
__device__ __forceinline__ bool winner_dead(u64 bv, const u64* cb, const u32* __restrict__ rc){
  u32 ev = 0xFFFFFu - (u32)(bv & 0xFFFFFu);
  u32 p  = rc[ev];
  if (ldu64(cb + (p >> 16)) != bv) return false;
  return ldu64(cb + (p & 0xFFFFu)) == bv;
}

__device__ __forceinline__ void pass_edge(uint4 en, u64 kpfx, const u64* cb, u64* nb,
            const u32* __restrict__ rc, int* __restrict__ craw, int* __restrict__ medge,
            uint4* __restrict__ nxt, u32* cslot){
  u64 k  = kpfx | ((u64)en.w << 20) | (u64)(0xFFFFFu - en.x);
  u64 br = ldu64(cb + en.y);
  u64 bc = ldu64(cb + en.z);
  if (br == k && bc == k){                       // locally dominant -> matched
    craw[en.z] = (int)en.y;
    medge[en.y] = (int)en.x;
    return;
  }
  bool dead;
  if (br == k)                   dead = winner_dead(bc, cb, rc);
  else if (bc == k || bc == br)  dead = winner_dead(br, cb, rc);
  else                           dead = winner_dead(br, cb, rc) || winner_dead(bc, cb, rc);
  if (!dead){                                    // survives: compact + seed next round
    u32 p = atomicAdd(cslot, 1u);
    nxt[p] = en;
    u64 k2 = k + (1ull << 52);                   // same score/id, next round prefix
    amax64(nb + en.y, k2);
    amax64(nb + en.z, k2);
  }
}

__global__ void __launch_bounds__(1024)
k_match(u32* hdr, const u32* __restrict__ rc, u64* b0, u64* b1,
        int* __restrict__ craw, int* __restrict__ medge,
        uint4* A0, uint4* A1, int E){
  cg::grid_group g = cg::this_grid();
  u32* cnt = hdr + 8;
  int tid = blockIdx.x*blockDim.x + threadIdx.x;
  int nt  = gridDim.x*blockDim.x;
  u32 m = (u32)E;
  int R = 0;
  // ---- grid phase: 1 pass + 1 grid sync per round ----
  while (m > TAIL_M && R < MAX_ROUNDS){
    uint4* cur = (R & 1) ? A1 : A0;
    uint4* nxt = (R & 1) ? A0 : A1;
    u64*   cb  = (R & 1) ? b1 : b0;
    u64*   nb  = (R & 1) ? b0 : b1;
    if (tid == 0)
      __hip_atomic_store(cnt + ((R+2)&3), 0u, __ATOMIC_RELAXED, __HIP_MEMORY_SCOPE_AGENT);
    u32* cslot = cnt + ((R+1)&3);
    u64 kpfx = ((u64)(R+1)) << 52;
    for (u32 i = (u32)tid; i < m; i += (u32)nt)
      pass_edge(cur[i], kpfx, cb, nb, rc, craw, medge, nxt, cslot);
    g.sync();
    R++;
    m = ldu32(cnt + (R & 3));
  }
  // ---- tail phase: single block, block barriers only ----
  if (blockIdx.x != 0) return;
  while (m != 0u && R < MAX_ROUNDS){
    uint4* cur = (R & 1) ? A1 : A0;
    uint4* nxt = (R & 1) ? A0 : A1;
    u64*   cb  = (R & 1) ? b1 : b0;
    u64*   nb  = (R & 1) ? b0 : b1;
    if (threadIdx.x == 0)
      __hip_atomic_store(cnt + ((R+2)&3), 0u, __ATOMIC_RELAXED, __HIP_MEMORY_SCOPE_AGENT);
    u32* cslot = cnt + ((R+1)&3);
    u64 kpfx = ((u64)(R+1)) << 52;
    __syncthreads();
    for (u32 i = threadIdx.x; i < m; i += blockDim.x)
      pass_edge(cur[i], kpfx, cb, nb, rc, craw, medge, nxt, cslot);
    __syncthreads();
    R++;
    m = ldu32(cnt + (R & 3));
  }
}

__global__ void k_rootflag(const int* __restrict__ craw, u32* __restrict__ rf, int N){
  int i = blockIdx.x*blockDim.x + threadIdx.x;
  if (i < N) rf[i] = (craw[i] == i) ? 1u : 0u;
}

// ---------------- generic exclusive scan (n <= 65536) ----------------
__global__ void scan_p1(const u32* __restrict__ in, u32* __restrict__ out,
                        u32* __restrict__ bsums, const u32* __restrict__ nptr){
  __shared__ u32 sh[256];
  u32 n = *nptr;
  int t = threadIdx.x;
  u32 i = blockIdx.x*256u + (u32)t;
  u32 v = (i < n) ? in[i] : 0u;
  sh[t] = v; __syncthreads();
  for (int o = 1; o < 256; o <<= 1){
    u32 a = (t >= o) ? sh[t-o] : 0u;
    __syncthreads();
    sh[t] += a;
    __syncthreads();
  }
  if (i < n) out[i] = sh[t] - v;
  if (t == 255) bsums[blockIdx.x] = sh[255];
}
__global__ void scan_p2(u32* bsums, u32* total){
  __shared__ u32 sh[256];
  int t = threadIdx.x;
  u32 v = bsums[t];
  sh[t] = v; __syncthreads();
  for (int o = 1; o < 256; o <<= 1){
    u32 a = (t >= o) ? sh[t-o] : 0u;
    __syncthreads();
    sh[t] += a;
    __syncthreads();
  }
  bsums[t] = sh[t] - v;
  if (t == 255 && total) *total = sh[255];
}
__global__ void scan_p3(u32* out, const u32* __restrict__ bsums, const u32* __restrict__ nptr){
  u32 n = *nptr;
  u32 i = blockIdx.x*256u + threadIdx.x;
  if (i < n) out[i] += bsums[blockIdx.x];
}

// ---------------- final cluster ids (+ write cluster output) ----------------
__global__ void k_clusterout(const int* __restrict__ craw, const u32* __restrict__ newid,
                             int* __restrict__ clout, float* __restrict__ out,
                             size_t offC, int N){
  int i = blockIdx.x*blockDim.x + threadIdx.x;
  if (i < N){
    int cl = (int)newid[craw[i]];
    clout[i] = cl;
    out[offC + i] = (float)cl;
  }
}

__global__ void k_hist(const int* __restrict__ row, const int* __restrict__ clout,
                       u32* __restrict__ hist, int E){
  int i0 = blockIdx.x*blockDim.x + threadIdx.x;
  int nt = gridDim.x*blockDim.x;
  for (int e = i0; e < E; e += nt) atomicAdd(&hist[clout[row[e]]], 1u);
}

__global__ void k_scatter(const int* __restrict__ row, const int* __restrict__ col,
                          const int* __restrict__ clout, const u32* __restrict__ segoff,
                          u32* __restrict__ cur2, u32* __restrict__ ccbuf, int E){
  int i0 = blockIdx.x*blockDim.x + threadIdx.x;
  int nt = gridDim.x*blockDim.x;
  for (int e = i0; e < E; e += nt){
    int cr = clout[row[e]];
    u32 pos = segoff[cr] + atomicAdd(&cur2[cr], 1u);
    ccbuf[pos] = (u32)clout[col[e]];
  }
}

// ---------------- per-segment sort + dedup (1 wave / block) ----------------
__global__ void k_segsort(const u32* __restrict__ hdr, const u32* __restrict__ hist,
                          const u32* __restrict__ segoff, u32* __restrict__ ccbuf,
                          u32* __restrict__ uniqcnt){
  int c = (int)hdr[2];
  __shared__ u32 sh[1024];
  int lane = threadIdx.x;   // block = 64 threads
  for (int seg = blockIdx.x; seg < c; seg += gridDim.x){
    int n = (int)hist[seg];
    if (n <= 0){ if (lane == 0) uniqcnt[seg] = 0u; continue; }
    u32 off = segoff[seg];
    if (n <= 64){
      u32 v = (lane < n) ? ccbuf[off + lane] : 0xFFFFFFFFu;
      #pragma unroll
      for (int k = 2; k <= 64; k <<= 1)
        for (int j = k >> 1; j > 0; j >>= 1){
          u32 p = __shfl_xor(v, j);
          bool up  = ((lane & k) == 0);
          bool low = ((lane & j) == 0);
          u32 mn = v < p ? v : p, mx = v < p ? p : v;
          v = (up == low) ? mn : mx;
        }
      u32 pv = __shfl_up(v, 1);
      bool un = (lane < n) && (lane == 0 || v != pv);
      u64 bal = __ballot(un);
      int cnt = __popcll(bal);
      int rk  = __popcll(bal & ((1ull << lane) - 1ull));
      if (un) ccbuf[off + rk] = v;
      if (lane == 0) uniqcnt[seg] = (u32)cnt;
    } else {
      int nn = n > 1024 ? 1024 : n;
      for (int i = lane; i < nn; i += 64) sh[i] = ccbuf[off + i];
      __syncthreads();
      for (int p = 0; p < nn; p++){
        int st = p & 1;
        for (int i = lane; 2*i + 1 + st < nn; i += 64){
          int a = 2*i + st;
          u32 x0 = sh[a], x1 = sh[a+1];
          if (x0 > x1){ sh[a] = x1; sh[a+1] = x0; }
        }
        __syncthreads();
      }
      if (lane == 0){
        int cnt = 0; u32 prev = 0u;
        for (int i = 0; i < nn; i++){
          u32 xv = sh[i];
          if (i == 0 || xv != prev){ ccbuf[off + cnt] = xv; cnt++; prev = xv; }
        }
        uniqcnt[seg] = (u32)cnt;
      }
      __syncthreads();
    }
  }
}

// ---------------- write new_edge_index ----------------
__global__ void k_writeedges(const u32* __restrict__ hdr, const u32* __restrict__ segoff,
                             const u32* __restrict__ uniqcnt, const u32* __restrict__ uniqoff,
                             const u32* __restrict__ ccbuf, float* __restrict__ out){
  int c = (int)hdr[2]; u32 Ep = hdr[3];
  size_t base = (size_t)c * CH_;
  int gw   = (blockIdx.x*blockDim.x + threadIdx.x) >> 6;
  int lane = threadIdx.x & 63;
  int nw   = (gridDim.x*blockDim.x) >> 6;
  for (int seg = gw; seg < c; seg += nw){
    int cnt = (int)uniqcnt[seg];
    u32 so = segoff[seg], uo = uniqoff[seg];
    for (int j = lane; j < cnt; j += 64){
      u32 cc = ccbuf[so + j];
      out[base + uo + j]              = (float)seg;
      out[base + (size_t)Ep + uo + j] = (float)cc;
    }
  }
}

// ---------------- new_x / new_batch / new_edge_score (wave per root) ----------------
__global__ void k_final(const u32* __restrict__ hdr, const int* __restrict__ craw,
                        const u32* __restrict__ newid, const int* __restrict__ medge,
                        const int* __restrict__ row, const int* __restrict__ col,
                        const float* __restrict__ score, const int* __restrict__ batch,
                        const float* __restrict__ x, float* __restrict__ out, int N){
  int c = (int)hdr[2]; u32 Ep = hdr[3];
  size_t offB = (size_t)c * CH_ + 2ull * (size_t)Ep;
  size_t offS = offB + (size_t)c;
  int gw   = (blockIdx.x*blockDim.x + threadIdx.x) >> 6;
  int lane = threadIdx.x & 63;
  int nw   = (gridDim.x*blockDim.x) >> 6;
  for (int i = gw; i < N; i += nw){
    if (craw[i] != i) continue;
    int j = (int)newid[i];
    int e = medge[i];
    int lo = i, hi = i; float sc = 1.0f;
    if (e >= 0){
      int r = row[e], cc = col[e];
      lo = min(r, cc); hi = max(r, cc);
      sc = score[e];
    }
    float v0 = x[(size_t)lo*CH_ + lane];
    float v1 = x[(size_t)lo*CH_ + 64 + lane];
    if (hi != lo){ v0 += x[(size_t)hi*CH_ + lane]; v1 += x[(size_t)hi*CH_ + 64 + lane]; }
    out[(size_t)j*CH_ + lane]      = v0 * sc;
    out[(size_t)j*CH_ + 64 + lane] = v1 * sc;
    if (lane == 0){
      out[offB + j] = (float)batch[hi];  // CPU-XLA scatter: last (max-index) member wins
      out[offS + j] = sc;
    }
  }
}

extern "C" void kernel_launch(void* const* d_in, const int* in_sizes, int n_in,
                              void* d_out, int out_size, void* d_ws, size_t ws_size,
                              hipStream_t stream) {
  const float* x     = (const float*)d_in[0];
  const int*   eidx  = (const int*)d_in[1];
  const int*   batch = (const int*)d_in[2];
  const float* lw    = (const float*)d_in[3];
  const float* lb    = (const float*)d_in[4];

  int N = in_sizes[0] / CH_;
  int E = in_sizes[1] / 2;
  const int* row = eidx;
  const int* col = eidx + E;
  float* out = (float*)d_out;

  // ---- workspace carve ----
  char* w = (char*)d_ws;
  size_t off = 0;
  auto carve = [&](size_t bytes) -> void* {
    void* p = w + off;
    off += (bytes + 255) & ~(size_t)255;
    return p;
  };
  u32*    hdr    = (u32*)   carve(256);
  double* den    = (double*)carve((size_t)N*8);
  u64*    b0     = (u64*)   carve((size_t)N*8);
  u64*    b1     = (u64*)   carve((size_t)N*8);
  float*  s      = (float*) carve((size_t)N*4);
  float*  t      = (float*) carve((size_t)N*4);
  float*  rawex  = (float*) carve((size_t)E*4);   // becomes score
  u32*    mxbits = (u32*)   carve((size_t)N*4);
  int*    craw   = (int*)   carve((size_t)N*4);
  u32*    rf     = (u32*)   carve((size_t)N*4);
  u32*    newid  = (u32*)   carve((size_t)N*4);
  int*    medge  = (int*)   carve((size_t)N*4);
  int*    clout  = (int*)   carve((size_t)N*4);
  u32*    rc     = (u32*)   carve((size_t)E*4);
  uint4*  A0     = (uint4*) carve((size_t)E*16);
  uint4*  A1     = (uint4*) carve((size_t)E*16);
  u32*    bsums  = (u32*)   carve(256*4);
  // alias post-match scratch into the (then-dead) A0 region
  char* a = (char*)A0;
  size_t aoff = 0;
  auto acarve = [&](size_t bytes) -> void* {
    void* p = a + aoff;
    aoff += (bytes + 255) & ~(size_t)255;
    return p;
  };
  u32* ccbuf   = (u32*)acarve((size_t)E*4);
  u32* hist    = (u32*)acarve((size_t)(N+64)*4);
  u32* segoff  = (u32*)acarve((size_t)(N+64)*4);
  u32* cur2    = (u32*)acarve((size_t)(N+64)*4);
  u32* uniqcnt = (u32*)acarve((size_t)(N+64)*4);
  u32* uniqoff = (u32*)acarve((size_t)(N+64)*4);
  (void)ws_size; (void)n_in;

  int nbE = (E + 255) / 256;
  int nbN = (N + 255) / 256;

  k_init<<<512, 256, 0, stream>>>(hdr, mxbits, den, b0, b1, craw, medge, N);
  k_dots<<<(N + 3)/4, 256, 0, stream>>>(x, lw, s, t, N);
  k_rawmax<<<nbE, 256, 0, stream>>>(s, t, row, col, lb, rawex, mxbits, E);
  k_exden<<<nbE, 256, 0, stream>>>(col, mxbits, rawex, den, E);
  k_scorekey<<<nbE, 256, 0, stream>>>(row, col, rawex, den, rc, A0, b0, E);

  {
    // 128 blocks: grid-sync cost scales with block count; the per-round pass
    // needs only ~6 edges/thread at m=800K (independent iterations, ILP-hidden).
    void* kargs[] = { &hdr, (void*)&rc, &b0, &b1, &craw, &medge, &A0, &A1, &E };
    hipLaunchCooperativeKernel((void*)k_match, dim3(128), dim3(1024), kargs, 0, stream);
  }

  k_rootflag<<<nbN, 256, 0, stream>>>(craw, rf, N);

  // scan rootflag -> newid ; total -> hdr[2] (= c). n from hdr[6] (= N)
  scan_p1<<<256, 256, 0, stream>>>(rf, newid, bsums, &hdr[6]);
  scan_p2<<<1, 256, 0, stream>>>(bsums, &hdr[2]);
  scan_p3<<<256, 256, 0, stream>>>(newid, bsums, &hdr[6]);

  k_clusterout<<<nbN, 256, 0, stream>>>(craw, newid, clout, out, (size_t)(out_size - N), N);
  k_init2<<<(N + 64 + 255)/256, 256, 0, stream>>>(hist, cur2, uniqcnt, N + 64);
  k_hist<<<nbE, 256, 0, stream>>>(row, clout, hist, E);

  // scan hist -> segoff ; n from hdr[2] (= c)
  scan_p1<<<256, 256, 0, stream>>>(hist, segoff, bsums, &hdr[2]);
  scan_p2<<<1, 256, 0, stream>>>(bsums, &hdr[4]);
  scan_p3<<<256, 256, 0, stream>>>(segoff, bsums, &hdr[2]);

  k_scatter<<<nbE, 256, 0, stream>>>(row, col, clout, segoff, cur2, ccbuf, E);
  k_segsort<<<4096, 64, 0, stream>>>(hdr, hist, segoff, ccbuf, uniqcnt);

  // scan uniqcnt -> uniqoff ; total -> hdr[3] (= E')
  scan_p1<<<256, 256, 0, stream>>>(uniqcnt, uniqoff, bsums, &hdr[2]);
  scan_p2<<<1, 256, 0, stream>>>(bsums, &hdr[3]);
  scan_p3<<<256, 256, 0, stream>>>(uniqoff, bsums, &hdr[2]);

  k_writeedges<<<2048, 256, 0, stream>>>(hdr, segoff, uniqcnt, uniqoff, ccbuf, out);
  k_final<<<4096, 256, 0, stream>>>(hdr, craw, newid, medge, row, col, rawex, batch, x, out, N);
}

// Round 5
// 1311.801 us; speedup vs baseline: 4.4199x; 1.0099x over previous
//
#include <hip/hip_runtime.h>
#include <hip/hip_cooperative_groups.h>

namespace cg = cooperative_groups;

typedef unsigned int u32;
typedef unsigned long long u64;

#define CH_ 128
#define TAIL_M 12288u
#define MAX_ROUNDS 4000
#define BT 4

__device__ __forceinline__ u32 f2ord(float f){
  u32 u = __float_as_uint(f);
  return ((int)u < 0) ? ~u : (u | 0x80000000u);
}
__device__ __forceinline__ float ord2f(u32 u){
  return (u & 0x80000000u) ? __uint_as_float(u & 0x7FFFFFFFu) : __uint_as_float(~u);
}
__device__ __forceinline__ u32 ldu32(const u32* p){
  return __hip_atomic_load(p, __ATOMIC_RELAXED, __HIP_MEMORY_SCOPE_AGENT);
}
__device__ __forceinline__ u64 ldu64(const u64* p){
  return __hip_atomic_load(p, __ATOMIC_RELAXED, __HIP_MEMORY_SCOPE_AGENT);
}
// atomicMax with cheap hi-word pre-check. Plain (possibly stale) load is
// monotonicity-safe: stale <= current, so skipping when stale_hi > k_hi is safe.
__device__ __forceinline__ void amax64(u64* a, u64 k){
  u32 hi = ((const u32*)a)[1];
  if (hi <= (u32)(k >> 32)) atomicMax((unsigned long long*)a, (unsigned long long)k);
}

// ---------------- init ----------------
__global__ void k_init(u32* hdr, u32* mxbits, double* den, u64* b0, u64* b1,
                       int* craw, int* medge, int N){
  int i0 = blockIdx.x*blockDim.x + threadIdx.x;
  int nt = gridDim.x*blockDim.x;
  for (int v = i0; v < N; v += nt){
    mxbits[v]=0u; den[v]=0.0; b0[v]=0ull; b1[v]=0ull; craw[v]=v; medge[v]=-1;
  }
  if (i0 == 0){
    for (int i = 0; i < 16; i++) hdr[i] = 0u;
    hdr[6] = (u32)N;
  }
}

// zero hist/cur2/uniqcnt AFTER k_match (they alias the A0 region)
__global__ void k_init2(u32* hist, u32* cur2, u32* uniqcnt, int n){
  int i = blockIdx.x*blockDim.x + threadIdx.x;
  if (i < n){ hist[i]=0u; cur2[i]=0u; uniqcnt[i]=0u; }
}

// ---------------- per-node dot products: s=x.w1, t=x.w2 ----------------
__global__ void k_dots(const float* __restrict__ x, const float* __restrict__ lw,
                       float* __restrict__ s, float* __restrict__ t, int N){
  int wid = threadIdx.x >> 6, lane = threadIdx.x & 63;
  int node = blockIdx.x*4 + wid;
  if (node >= N) return;
  const float* xr = x + (size_t)node*CH_;
  float xa = xr[lane], xb = xr[64+lane];
  float sv = xa*lw[lane]      + xb*lw[64+lane];
  float tv = xa*lw[128+lane]  + xb*lw[192+lane];
  #pragma unroll
  for (int m = 1; m < 64; m <<= 1){ sv += __shfl_xor(sv, m); tv += __shfl_xor(tv, m); }
  if (lane == 0){ s[node]=sv; t[node]=tv; }
}

// ---------------- raw score + segment max over col ----------------
__global__ void k_rawmax(const float* __restrict__ s, const float* __restrict__ t,
                         const int* __restrict__ row, const int* __restrict__ col,
                         const float* __restrict__ lb, float* __restrict__ rawex,
                         u32* __restrict__ mxbits, int E){
  float b = lb[0];
  int i0 = blockIdx.x*blockDim.x + threadIdx.x;
  int nt = gridDim.x*blockDim.x;
  for (int e = i0; e < E; e += nt){
    float raw = (s[row[e]] + t[col[e]]) + b;
    rawex[e] = raw;
    atomicMax(&mxbits[col[e]], f2ord(raw));
  }
}

// ---------------- ex = exp(raw-mx), den = segsum(ex) in f64 ----------------
__global__ void k_exden(const int* __restrict__ col, const u32* __restrict__ mxbits,
                        float* __restrict__ rawex, double* __restrict__ den, int E){
  int i0 = blockIdx.x*blockDim.x + threadIdx.x;
  int nt = gridDim.x*blockDim.x;
  for (int e = i0; e < E; e += nt){
    int c = col[e];
    float ex = expf(rawex[e] - ord2f(mxbits[c]));
    rawex[e] = ex;
    atomicAdd(&den[c], (double)ex);
  }
}

// ---------------- score (in-place), packed entries, prologue best(round 0) ----
__global__ void k_scorekey(const int* __restrict__ row, const int* __restrict__ col,
                           float* __restrict__ rawex, const double* __restrict__ den,
                           u32* __restrict__ rc, uint4* __restrict__ A0,
                           u64* b0, int E){
  int i0 = blockIdx.x*blockDim.x + threadIdx.x;
  int nt = gridDim.x*blockDim.x;
  for (int e = i0; e < E; e += nt){
    int r = row[e], c = col[e];
    float d = (float)den[c];
    float sc = rawex[e]/d + 0.5f;          // > 0 -> float bits order-monotone
    rawex[e] = sc;                          // rawex now holds the score
    u32 sb = __float_as_uint(sc);
    rc[e] = ((u32)r << 16) | (u32)c;        // N < 65536
    A0[e] = make_uint4((u32)e, (u32)r, (u32)c, sb);
    u64 k = (1ull << 52) | ((u64)sb << 20) | (u64)(0xFFFFFu - (u32)e); // round 0 key
    amax64(b0 + r, k);
    amax64(b0 + c, k);
  }
}

// ---------------- batched matching pass: stage-pipelined for MLP ----------------
// Per-edge semantics identical to the serial pass_edge (pure load reordering of
// monotone relaxed-atomic data): matched if both endpoints' best == our key;
// dead if any endpoint's winner edge is mutually dominant; else survive:
// compact into nxt and seed next round's best buffer.
__device__ __forceinline__ void pass_batched(const uint4* cur, u32 m, u32 tid, u32 nt,
    u64 kpfx, const u64* cb, u64* nb, const u32* __restrict__ rc,
    int* __restrict__ craw, int* __restrict__ medge,
    uint4* nxt, u32* cslot){
  u32 chunk = nt * (u32)BT;
  for (u32 base = 0; base < m; base += chunk){
    uint4 en[BT]; bool val[BT]; bool two[BT];
    u64 w1[BT], w2[BT]; u32 p1[BT], p2[BT];
    u64 br[BT], bc[BT];
    u64 q1r[BT], q1c[BT], q2r[BT], q2c[BT];
    // stage 1: coalesced entry loads
    #pragma unroll
    for (int j = 0; j < BT; j++){
      u32 i = base + tid + (u32)j*nt;
      val[j] = (i < m);
      if (val[j]) en[j] = cur[i];
    }
    // stage 2: best-buffer loads (independent)
    #pragma unroll
    for (int j = 0; j < BT; j++) if (val[j]){
      br[j] = ldu64(cb + en[j].y);
      bc[j] = ldu64(cb + en[j].z);
    }
    // stage 3: classify; matched edges resolve now
    #pragma unroll
    for (int j = 0; j < BT; j++) if (val[j]){
      u64 k = kpfx | ((u64)en[j].w << 20) | (u64)(0xFFFFFu - en[j].x);
      if (br[j] == k && bc[j] == k){
        craw[en[j].z] = (int)en[j].y; medge[en[j].y] = (int)en[j].x;
        val[j] = false;
      } else if (br[j] == k){ w1[j] = bc[j]; two[j] = false; }
      else if (bc[j] == k || bc[j] == br[j]){ w1[j] = br[j]; two[j] = false; }
      else { w1[j] = br[j]; w2[j] = bc[j]; two[j] = true; }
    }
    // stage 4: winner endpoint lookups (independent)
    #pragma unroll
    for (int j = 0; j < BT; j++) if (val[j]){
      p1[j] = rc[0xFFFFFu - (u32)(w1[j] & 0xFFFFFu)];
      if (two[j]) p2[j] = rc[0xFFFFFu - (u32)(w2[j] & 0xFFFFFu)];
    }
    // stage 5: winner mutual-dominance loads (independent)
    #pragma unroll
    for (int j = 0; j < BT; j++) if (val[j]){
      q1r[j] = ldu64(cb + (p1[j] >> 16));
      q1c[j] = ldu64(cb + (p1[j] & 0xFFFFu));
      if (two[j]){ q2r[j] = ldu64(cb + (p2[j] >> 16)); q2c[j] = ldu64(cb + (p2[j] & 0xFFFFu)); }
    }
    // stage 6: resolve survivors
    #pragma unroll
    for (int j = 0; j < BT; j++) if (val[j]){
      bool dead = (q1r[j] == w1[j]) & (q1c[j] == w1[j]);
      if (two[j]) dead = dead || ((q2r[j] == w2[j]) & (q2c[j] == w2[j]));
      if (!dead){
        u32 p = atomicAdd(cslot, 1u);
        nxt[p] = en[j];
        u64 k2 = (kpfx + (1ull << 52)) | ((u64)en[j].w << 20) | (u64)(0xFFFFFu - en[j].x);
        amax64(nb + en[j].y, k2);
        amax64(nb + en[j].z, k2);
      }
    }
  }
}

__global__ void __launch_bounds__(1024)
k_match(u32* hdr, const u32* __restrict__ rc, u64* b0, u64* b1,
        int* __restrict__ craw, int* __restrict__ medge,
        uint4* A0, uint4* A1, int E){
  cg::grid_group g = cg::this_grid();
  u32* cnt = hdr + 8;
  u32 tid = (u32)(blockIdx.x*blockDim.x + threadIdx.x);
  u32 nt  = (u32)(gridDim.x*blockDim.x);
  u32 m = (u32)E;
  int R = 0;
  // ---- grid phase: 1 pass + 1 grid sync per round ----
  while (m > TAIL_M && R < MAX_ROUNDS){
    uint4* cur = (R & 1) ? A1 : A0;
    uint4* nxt = (R & 1) ? A0 : A1;
    u64*   cb  = (R & 1) ? b1 : b0;
    u64*   nb  = (R & 1) ? b0 : b1;
    if (tid == 0)
      __hip_atomic_store(cnt + ((R+2)&3), 0u, __ATOMIC_RELAXED, __HIP_MEMORY_SCOPE_AGENT);
    u32* cslot = cnt + ((R+1)&3);
    u64 kpfx = ((u64)(R+1)) << 52;
    pass_batched(cur, m, tid, nt, kpfx, cb, nb, rc, craw, medge, nxt, cslot);
    g.sync();
    R++;
    m = ldu32(cnt + (R & 3));
  }
  // ---- tail phase: single block, block barriers only ----
  if (blockIdx.x != 0) return;
  while (m != 0u && R < MAX_ROUNDS){
    uint4* cur = (R & 1) ? A1 : A0;
    uint4* nxt = (R & 1) ? A0 : A1;
    u64*   cb  = (R & 1) ? b1 : b0;
    u64*   nb  = (R & 1) ? b0 : b1;
    if (threadIdx.x == 0)
      __hip_atomic_store(cnt + ((R+2)&3), 0u, __ATOMIC_RELAXED, __HIP_MEMORY_SCOPE_AGENT);
    u32* cslot = cnt + ((R+1)&3);
    u64 kpfx = ((u64)(R+1)) << 52;
    __syncthreads();
    pass_batched(cur, m, (u32)threadIdx.x, (u32)blockDim.x, kpfx, cb, nb, rc,
                 craw, medge, nxt, cslot);
    __syncthreads();
    R++;
    m = ldu32(cnt + (R & 3));
  }
}

__global__ void k_rootflag(const int* __restrict__ craw, u32* __restrict__ rf, int N){
  int i = blockIdx.x*blockDim.x + threadIdx.x;
  if (i < N) rf[i] = (craw[i] == i) ? 1u : 0u;
}

// ---------------- generic exclusive scan (n <= 65536) ----------------
__global__ void scan_p1(const u32* __restrict__ in, u32* __restrict__ out,
                        u32* __restrict__ bsums, const u32* __restrict__ nptr){
  __shared__ u32 sh[256];
  u32 n = *nptr;
  int t = threadIdx.x;
  u32 i = blockIdx.x*256u + (u32)t;
  u32 v = (i < n) ? in[i] : 0u;
  sh[t] = v; __syncthreads();
  for (int o = 1; o < 256; o <<= 1){
    u32 a = (t >= o) ? sh[t-o] : 0u;
    __syncthreads();
    sh[t] += a;
    __syncthreads();
  }
  if (i < n) out[i] = sh[t] - v;
  if (t == 255) bsums[blockIdx.x] = sh[255];
}
__global__ void scan_p2(u32* bsums, u32* total){
  __shared__ u32 sh[256];
  int t = threadIdx.x;
  u32 v = bsums[t];
  sh[t] = v; __syncthreads();
  for (int o = 1; o < 256; o <<= 1){
    u32 a = (t >= o) ? sh[t-o] : 0u;
    __syncthreads();
    sh[t] += a;
    __syncthreads();
  }
  bsums[t] = sh[t] - v;
  if (t == 255 && total) *total = sh[255];
}
__global__ void scan_p3(u32* out, const u32* __restrict__ bsums, const u32* __restrict__ nptr){
  u32 n = *nptr;
  u32 i = blockIdx.x*256u + threadIdx.x;
  if (i < n) out[i] += bsums[blockIdx.x];
}

// ---------------- final cluster ids (+ write cluster output) ----------------
__global__ void k_clusterout(const int* __restrict__ craw, const u32* __restrict__ newid,
                             int* __restrict__ clout, float* __restrict__ out,
                             size_t offC, int N){
  int i = blockIdx.x*blockDim.x + threadIdx.x;
  if (i < N){
    int cl = (int)newid[craw[i]];
    clout[i] = cl;
    out[offC + i] = (float)cl;
  }
}

__global__ void k_hist(const int* __restrict__ row, const int* __restrict__ clout,
                       u32* __restrict__ hist, int E){
  int i0 = blockIdx.x*blockDim.x + threadIdx.x;
  int nt = gridDim.x*blockDim.x;
  for (int e = i0; e < E; e += nt) atomicAdd(&hist[clout[row[e]]], 1u);
}

__global__ void k_scatter(const int* __restrict__ row, const int* __restrict__ col,
                          const int* __restrict__ clout, const u32* __restrict__ segoff,
                          u32* __restrict__ cur2, u32* __restrict__ ccbuf, int E){
  int i0 = blockIdx.x*blockDim.x + threadIdx.x;
  int nt = gridDim.x*blockDim.x;
  for (int e = i0; e < E; e += nt){
    int cr = clout[row[e]];
    u32 pos = segoff[cr] + atomicAdd(&cur2[cr], 1u);
    ccbuf[pos] = (u32)clout[col[e]];
  }
}

// ---------------- per-segment sort + dedup (1 wave / block) ----------------
__global__ void k_segsort(const u32* __restrict__ hdr, const u32* __restrict__ hist,
                          const u32* __restrict__ segoff, u32* __restrict__ ccbuf,
                          u32* __restrict__ uniqcnt){
  int c = (int)hdr[2];
  __shared__ u32 sh[1024];
  int lane = threadIdx.x;   // block = 64 threads
  for (int seg = blockIdx.x; seg < c; seg += gridDim.x){
    int n = (int)hist[seg];
    if (n <= 0){ if (lane == 0) uniqcnt[seg] = 0u; continue; }
    u32 off = segoff[seg];
    if (n <= 64){
      u32 v = (lane < n) ? ccbuf[off + lane] : 0xFFFFFFFFu;
      #pragma unroll
      for (int k = 2; k <= 64; k <<= 1)
        for (int j = k >> 1; j > 0; j >>= 1){
          u32 p = __shfl_xor(v, j);
          bool up  = ((lane & k) == 0);
          bool low = ((lane & j) == 0);
          u32 mn = v < p ? v : p, mx = v < p ? p : v;
          v = (up == low) ? mn : mx;
        }
      u32 pv = __shfl_up(v, 1);
      bool un = (lane < n) && (lane == 0 || v != pv);
      u64 bal = __ballot(un);
      int cnt = __popcll(bal);
      int rk  = __popcll(bal & ((1ull << lane) - 1ull));
      if (un) ccbuf[off + rk] = v;
      if (lane == 0) uniqcnt[seg] = (u32)cnt;
    } else {
      int nn = n > 1024 ? 1024 : n;
      for (int i = lane; i < nn; i += 64) sh[i] = ccbuf[off + i];
      __syncthreads();
      for (int p = 0; p < nn; p++){
        int st = p & 1;
        for (int i = lane; 2*i + 1 + st < nn; i += 64){
          int a = 2*i + st;
          u32 x0 = sh[a], x1 = sh[a+1];
          if (x0 > x1){ sh[a] = x1; sh[a+1] = x0; }
        }
        __syncthreads();
      }
      if (lane == 0){
        int cnt = 0; u32 prev = 0u;
        for (int i = 0; i < nn; i++){
          u32 xv = sh[i];
          if (i == 0 || xv != prev){ ccbuf[off + cnt] = xv; cnt++; prev = xv; }
        }
        uniqcnt[seg] = (u32)cnt;
      }
      __syncthreads();
    }
  }
}

// ---------------- write new_edge_index ----------------
__global__ void k_writeedges(const u32* __restrict__ hdr, const u32* __restrict__ segoff,
                             const u32* __restrict__ uniqcnt, const u32* __restrict__ uniqoff,
                             const u32* __restrict__ ccbuf, float* __restrict__ out){
  int c = (int)hdr[2]; u32 Ep = hdr[3];
  size_t base = (size_t)c * CH_;
  int gw   = (blockIdx.x*blockDim.x + threadIdx.x) >> 6;
  int lane = threadIdx.x & 63;
  int nw   = (gridDim.x*blockDim.x) >> 6;
  for (int seg = gw; seg < c; seg += nw){
    int cnt = (int)uniqcnt[seg];
    u32 so = segoff[seg], uo = uniqoff[seg];
    for (int j = lane; j < cnt; j += 64){
      u32 cc = ccbuf[so + j];
      out[base + uo + j]              = (float)seg;
      out[base + (size_t)Ep + uo + j] = (float)cc;
    }
  }
}

// ---------------- new_x / new_batch / new_edge_score (wave per root) ----------------
__global__ void k_final(const u32* __restrict__ hdr, const int* __restrict__ craw,
                        const u32* __restrict__ newid, const int* __restrict__ medge,
                        const int* __restrict__ row, const int* __restrict__ col,
                        const float* __restrict__ score, const int* __restrict__ batch,
                        const float* __restrict__ x, float* __restrict__ out, int N){
  int c = (int)hdr[2]; u32 Ep = hdr[3];
  size_t offB = (size_t)c * CH_ + 2ull * (size_t)Ep;
  size_t offS = offB + (size_t)c;
  int gw   = (blockIdx.x*blockDim.x + threadIdx.x) >> 6;
  int lane = threadIdx.x & 63;
  int nw   = (gridDim.x*blockDim.x) >> 6;
  for (int i = gw; i < N; i += nw){
    if (craw[i] != i) continue;
    int j = (int)newid[i];
    int e = medge[i];
    int lo = i, hi = i; float sc = 1.0f;
    if (e >= 0){
      int r = row[e], cc = col[e];
      lo = min(r, cc); hi = max(r, cc);
      sc = score[e];
    }
    float v0 = x[(size_t)lo*CH_ + lane];
    float v1 = x[(size_t)lo*CH_ + 64 + lane];
    if (hi != lo){ v0 += x[(size_t)hi*CH_ + lane]; v1 += x[(size_t)hi*CH_ + 64 + lane]; }
    out[(size_t)j*CH_ + lane]      = v0 * sc;
    out[(size_t)j*CH_ + 64 + lane] = v1 * sc;
    if (lane == 0){
      out[offB + j] = (float)batch[hi];  // CPU-XLA scatter: last (max-index) member wins
      out[offS + j] = sc;
    }
  }
}

extern "C" void kernel_launch(void* const* d_in, const int* in_sizes, int n_in,
                              void* d_out, int out_size, void* d_ws, size_t ws_size,
                              hipStream_t stream) {
  const float* x     = (const float*)d_in[0];
  const int*   eidx  = (const int*)d_in[1];
  const int*   batch = (const int*)d_in[2];
  const float* lw    = (const float*)d_in[3];
  const float* lb    = (const float*)d_in[4];

  int N = in_sizes[0] / CH_;
  int E = in_sizes[1] / 2;
  const int* row = eidx;
  const int* col = eidx + E;
  float* out = (float*)d_out;

  // ---- workspace carve ----
  char* w = (char*)d_ws;
  size_t off = 0;
  auto carve = [&](size_t bytes) -> void* {
    void* p = w + off;
    off += (bytes + 255) & ~(size_t)255;
    return p;
  };
  u32*    hdr    = (u32*)   carve(256);
  double* den    = (double*)carve((size_t)N*8);
  u64*    b0     = (u64*)   carve((size_t)N*8);
  u64*    b1     = (u64*)   carve((size_t)N*8);
  float*  s      = (float*) carve((size_t)N*4);
  float*  t      = (float*) carve((size_t)N*4);
  float*  rawex  = (float*) carve((size_t)E*4);   // becomes score
  u32*    mxbits = (u32*)   carve((size_t)N*4);
  int*    craw   = (int*)   carve((size_t)N*4);
  u32*    rf     = (u32*)   carve((size_t)N*4);
  u32*    newid  = (u32*)   carve((size_t)N*4);
  int*    medge  = (int*)   carve((size_t)N*4);
  int*    clout  = (int*)   carve((size_t)N*4);
  u32*    rc     = (u32*)   carve((size_t)E*4);
  uint4*  A0     = (uint4*) carve((size_t)E*16);
  uint4*  A1     = (uint4*) carve((size_t)E*16);
  u32*    bsums  = (u32*)   carve(256*4);
  // alias post-match scratch into the (then-dead) A0 region
  char* a = (char*)A0;
  size_t aoff = 0;
  auto acarve = [&](size_t bytes) -> void* {
    void* p = a + aoff;
    aoff += (bytes + 255) & ~(size_t)255;
    return p;
  };
  u32* ccbuf   = (u32*)acarve((size_t)E*4);
  u32* hist    = (u32*)acarve((size_t)(N+64)*4);
  u32* segoff  = (u32*)acarve((size_t)(N+64)*4);
  u32* cur2    = (u32*)acarve((size_t)(N+64)*4);
  u32* uniqcnt = (u32*)acarve((size_t)(N+64)*4);
  u32* uniqoff = (u32*)acarve((size_t)(N+64)*4);
  (void)ws_size; (void)n_in;

  int nbE = (E + 255) / 256;
  int nbN = (N + 255) / 256;

  k_init<<<512, 256, 0, stream>>>(hdr, mxbits, den, b0, b1, craw, medge, N);
  k_dots<<<(N + 3)/4, 256, 0, stream>>>(x, lw, s, t, N);
  k_rawmax<<<nbE, 256, 0, stream>>>(s, t, row, col, lb, rawex, mxbits, E);
  k_exden<<<nbE, 256, 0, stream>>>(col, mxbits, rawex, den, E);
  k_scorekey<<<nbE, 256, 0, stream>>>(row, col, rawex, den, rc, A0, b0, E);

  {
    // 128 blocks: grid-sync cost scales with block count; batched MLP pass
    // needs only ~2 chunks/round at m=800K.
    void* kargs[] = { &hdr, (void*)&rc, &b0, &b1, &craw, &medge, &A0, &A1, &E };
    hipLaunchCooperativeKernel((void*)k_match, dim3(128), dim3(1024), kargs, 0, stream);
  }

  k_rootflag<<<nbN, 256, 0, stream>>>(craw, rf, N);

  // scan rootflag -> newid ; total -> hdr[2] (= c). n from hdr[6] (= N)
  scan_p1<<<256, 256, 0, stream>>>(rf, newid, bsums, &hdr[6]);
  scan_p2<<<1, 256, 0, stream>>>(bsums, &hdr[2]);
  scan_p3<<<256, 256, 0, stream>>>(newid, bsums, &hdr[6]);

  k_clusterout<<<nbN, 256, 0, stream>>>(craw, newid, clout, out, (size_t)(out_size - N), N);
  k_init2<<<(N + 64 + 255)/256, 256, 0, stream>>>(hist, cur2, uniqcnt, N + 64);
  k_hist<<<nbE, 256, 0, stream>>>(row, clout, hist, E);

  // scan hist -> segoff ; n from hdr[2] (= c)
  scan_p1<<<256, 256, 0, stream>>>(hist, segoff, bsums, &hdr[2]);
  scan_p2<<<1, 256, 0, stream>>>(bsums, &hdr[4]);
  scan_p3<<<256, 256, 0, stream>>>(segoff, bsums, &hdr[2]);

  k_scatter<<<nbE, 256, 0, stream>>>(row, col, clout, segoff, cur2, ccbuf, E);
  k_segsort<<<4096, 64, 0, stream>>>(hdr, hist, segoff, ccbuf, uniqcnt);

  // scan uniqcnt -> uniqoff ; total -> hdr[3] (= E')
  scan_p1<<<256, 256, 0, stream>>>(uniqcnt, uniqoff, bsums, &hdr[2]);
  scan_p2<<<1, 256, 0, stream>>>(bsums, &hdr[3]);
  scan_p3<<<256, 256, 0, stream>>>(uniqoff, bsums, &hdr[2]);

  k_writeedges<<<2048, 256, 0, stream>>>(hdr, segoff, uniqcnt, uniqoff, ccbuf, out);
  k_final<<<4096, 256, 0, stream>>>(hdr, craw, newid, medge, row, col, rawex, batch, x, out, N);
}

// Round 6
// 1248.273 us; speedup vs baseline: 4.6448x; 1.0509x over previous
//
#include <hip/hip_runtime.h>

typedef unsigned int u32;
typedef unsigned long long u64;

#define CH_ 128
#define TAIL_M 12288u
#define MAX_ROUNDS 4000
#define BT 4
#define NBLK 128

__device__ __forceinline__ u32 f2ord(float f){
  u32 u = __float_as_uint(f);
  return ((int)u < 0) ? ~u : (u | 0x80000000u);
}
__device__ __forceinline__ float ord2f(u32 u){
  return (u & 0x80000000u) ? __uint_as_float(u & 0x7FFFFFFFu) : __uint_as_float(~u);
}
__device__ __forceinline__ u32 ldu32(const u32* p){
  return __hip_atomic_load(p, __ATOMIC_RELAXED, __HIP_MEMORY_SCOPE_AGENT);
}
__device__ __forceinline__ u64 ldu64(const u64* p){
  return __hip_atomic_load(p, __ATOMIC_RELAXED, __HIP_MEMORY_SCOPE_AGENT);
}
__device__ __forceinline__ void stu32(u32* p, u32 v){
  __hip_atomic_store(p, v, __ATOMIC_RELAXED, __HIP_MEMORY_SCOPE_AGENT);
}
__device__ __forceinline__ void stu64(u64* p, u64 v){
  __hip_atomic_store(p, v, __ATOMIC_RELAXED, __HIP_MEMORY_SCOPE_AGENT);
}
// LLC-point (agent-scope) 16B entry access as two u64 relaxed atomics.
__device__ __forceinline__ uint4 lde(const uint4* p){
  const u64* q = (const u64*)p;
  u64 a = ldu64(q), b = ldu64(q + 1);
  uint4 r; r.x=(u32)a; r.y=(u32)(a>>32); r.z=(u32)b; r.w=(u32)(b>>32);
  return r;
}
__device__ __forceinline__ void ste(uint4* p, uint4 v){
  u64* q = (u64*)p;
  stu64(q,     (u64)v.x | ((u64)v.y << 32));
  stu64(q + 1, (u64)v.z | ((u64)v.w << 32));
}
// atomicMax with cheap hi-word pre-check. Plain (possibly stale) load is
// monotonicity-safe: stale <= current, so skipping when stale_hi > k_hi is safe.
__device__ __forceinline__ void amax64(u64* a, u64 k){
  u32 hi = ((const u32*)a)[1];
  if (hi <= (u32)(k >> 32)) atomicMax((unsigned long long*)a, (unsigned long long)k);
}
// Fence-free grid barrier: monotone arrival counter at LLC. Each wave drains
// its vmem (no-return atomics included) before s_barrier; leader adds and
// spins on a relaxed agent load. No L2 writeback-invalidate anywhere.
__device__ __forceinline__ void gbar(u32* arrive, u32 target){
  asm volatile("s_waitcnt vmcnt(0) lgkmcnt(0)" ::: "memory");
  __syncthreads();
  if (threadIdx.x == 0){
    __hip_atomic_fetch_add(arrive, 1u, __ATOMIC_RELAXED, __HIP_MEMORY_SCOPE_AGENT);
    while (ldu32(arrive) < target) __builtin_amdgcn_s_sleep(2);
  }
  __syncthreads();
}

// ---------------- init ----------------
__global__ void k_init(u32* hdr, u32* mxbits, double* den, u64* b0, u64* b1,
                       int* craw, int* medge, int N){
  int i0 = blockIdx.x*blockDim.x + threadIdx.x;
  int nt = gridDim.x*blockDim.x;
  for (int v = i0; v < N; v += nt){
    mxbits[v]=0u; den[v]=0.0; b0[v]=0ull; b1[v]=0ull; craw[v]=v; medge[v]=-1;
  }
  if (i0 == 0){
    for (int i = 0; i < 64; i++) hdr[i] = 0u;
    hdr[6] = (u32)N;
  }
}

// zero hist/cur2/uniqcnt AFTER k_match (they alias the A0 region)
__global__ void k_init2(u32* hist, u32* cur2, u32* uniqcnt, int n){
  int i = blockIdx.x*blockDim.x + threadIdx.x;
  if (i < n){ hist[i]=0u; cur2[i]=0u; uniqcnt[i]=0u; }
}

// ---------------- per-node dot products: s=x.w1, t=x.w2 ----------------
__global__ void k_dots(const float* __restrict__ x, const float* __restrict__ lw,
                       float* __restrict__ s, float* __restrict__ t, int N){
  int wid = threadIdx.x >> 6, lane = threadIdx.x & 63;
  int node = blockIdx.x*4 + wid;
  if (node >= N) return;
  const float* xr = x + (size_t)node*CH_;
  float xa = xr[lane], xb = xr[64+lane];
  float sv = xa*lw[lane]      + xb*lw[64+lane];
  float tv = xa*lw[128+lane]  + xb*lw[192+lane];
  #pragma unroll
  for (int m = 1; m < 64; m <<= 1){ sv += __shfl_xor(sv, m); tv += __shfl_xor(tv, m); }
  if (lane == 0){ s[node]=sv; t[node]=tv; }
}

// ---------------- raw score + segment max over col ----------------
__global__ void k_rawmax(const float* __restrict__ s, const float* __restrict__ t,
                         const int* __restrict__ row, const int* __restrict__ col,
                         const float* __restrict__ lb, float* __restrict__ rawex,
                         u32* __restrict__ mxbits, int E){
  float b = lb[0];
  int i0 = blockIdx.x*blockDim.x + threadIdx.x;
  int nt = gridDim.x*blockDim.x;
  for (int e = i0; e < E; e += nt){
    float raw = (s[row[e]] + t[col[e]]) + b;
    rawex[e] = raw;
    atomicMax(&mxbits[col[e]], f2ord(raw));
  }
}

// ---------------- ex = exp(raw-mx), den = segsum(ex) in f64 ----------------
__global__ void k_exden(const int* __restrict__ col, const u32* __restrict__ mxbits,
                        float* __restrict__ rawex, double* __restrict__ den, int E){
  int i0 = blockIdx.x*blockDim.x + threadIdx.x;
  int nt = gridDim.x*blockDim.x;
  for (int e = i0; e < E; e += nt){
    int c = col[e];
    float ex = expf(rawex[e] - ord2f(mxbits[c]));
    rawex[e] = ex;
    atomicAdd(&den[c], (double)ex);
  }
}

// ---------------- score (in-place), packed entries, prologue best(round 0) ----
__global__ void k_scorekey(const int* __restrict__ row, const int* __restrict__ col,
                           float* __restrict__ rawex, const double* __restrict__ den,
                           u32* __restrict__ rc, uint4* __restrict__ A0,
                           u64* b0, int E){
  int i0 = blockIdx.x*blockDim.x + threadIdx.x;
  int nt = gridDim.x*blockDim.x;
  for (int e = i0; e < E; e += nt){
    int r = row[e], c = col[e];
    float d = (float)den[c];
    float sc = rawex[e]/d + 0.5f;          // > 0 -> float bits order-monotone
    rawex[e] = sc;                          // rawex now holds the score
    u32 sb = __float_as_uint(sc);
    rc[e] = ((u32)r << 16) | (u32)c;        // N < 65536
    A0[e] = make_uint4((u32)e, (u32)r, (u32)c, sb);
    u64 k = (1ull << 52) | ((u64)sb << 20) | (u64)(0xFFFFFu - (u32)e); // round 0 key
    amax64(b0 + r, k);
    amax64(b0 + c, k);
  }
}

// ---------------- batched matching pass: stage-pipelined for MLP ----------------
// Per-edge semantics identical to the serial pass_edge (pure load reordering of
// monotone relaxed-atomic data): matched if both endpoints' best == our key;
// dead if any endpoint's winner edge is mutually dominant; else survive:
// compact into nxt and seed next round's best buffer.
__device__ __forceinline__ void pass_batched(const uint4* cur, u32 m, u32 tid, u32 nt,
    u64 kpfx, const u64* cb, u64* nb, const u32* __restrict__ rc,
    int* __restrict__ craw, int* __restrict__ medge,
    uint4* nxt, u32* cslot){
  u32 chunk = nt * (u32)BT;
  for (u32 base = 0; base < m; base += chunk){
    uint4 en[BT]; bool val[BT]; bool two[BT];
    u64 w1[BT], w2[BT]; u32 p1[BT], p2[BT];
    u64 br[BT], bc[BT];
    u64 q1r[BT], q1c[BT], q2r[BT], q2c[BT];
    // stage 1: entry loads (LLC-point)
    #pragma unroll
    for (int j = 0; j < BT; j++){
      u32 i = base + tid + (u32)j*nt;
      val[j] = (i < m);
      if (val[j]) en[j] = lde(cur + i);
    }
    // stage 2: best-buffer loads (independent)
    #pragma unroll
    for (int j = 0; j < BT; j++) if (val[j]){
      br[j] = ldu64(cb + en[j].y);
      bc[j] = ldu64(cb + en[j].z);
    }
    // stage 3: classify; matched edges resolve now
    #pragma unroll
    for (int j = 0; j < BT; j++) if (val[j]){
      u64 k = kpfx | ((u64)en[j].w << 20) | (u64)(0xFFFFFu - en[j].x);
      if (br[j] == k && bc[j] == k){
        craw[en[j].z] = (int)en[j].y; medge[en[j].y] = (int)en[j].x;
        val[j] = false;
      } else if (br[j] == k){ w1[j] = bc[j]; two[j] = false; }
      else if (bc[j] == k || bc[j] == br[j]){ w1[j] = br[j]; two[j] = false; }
      else { w1[j] = br[j]; w2[j] = bc[j]; two[j] = true; }
    }
    // stage 4: winner endpoint lookups (independent)
    #pragma unroll
    for (int j = 0; j < BT; j++) if (val[j]){
      p1[j] = rc[0xFFFFFu - (u32)(w1[j] & 0xFFFFFu)];
      if (two[j]) p2[j] = rc[0xFFFFFu - (u32)(w2[j] & 0xFFFFFu)];
    }
    // stage 5: winner mutual-dominance loads (independent)
    #pragma unroll
    for (int j = 0; j < BT; j++) if (val[j]){
      q1r[j] = ldu64(cb + (p1[j] >> 16));
      q1c[j] = ldu64(cb + (p1[j] & 0xFFFFu));
      if (two[j]){ q2r[j] = ldu64(cb + (p2[j] >> 16)); q2c[j] = ldu64(cb + (p2[j] & 0xFFFFu)); }
    }
    // stage 6: resolve survivors
    #pragma unroll
    for (int j = 0; j < BT; j++) if (val[j]){
      bool dead = (q1r[j] == w1[j]) & (q1c[j] == w1[j]);
      if (two[j]) dead = dead || ((q2r[j] == w2[j]) & (q2c[j] == w2[j]));
      if (!dead){
        u32 p = atomicAdd(cslot, 1u);
        ste(nxt + p, en[j]);
        u64 k2 = (kpfx + (1ull << 52)) | ((u64)en[j].w << 20) | (u64)(0xFFFFFu - en[j].x);
        amax64(nb + en[j].y, k2);
        amax64(nb + en[j].z, k2);
      }
    }
  }
}

__global__ void __launch_bounds__(1024)
k_match(u32* hdr, const u32* __restrict__ rc, u64* b0, u64* b1,
        int* __restrict__ craw, int* __restrict__ medge,
        uint4* A0, uint4* A1, int E){
  u32* cnt    = hdr + 8;
  u32* arrive = hdr + 32;     // own cache line region, zeroed by k_init
  u32 tid = (u32)(blockIdx.x*blockDim.x + threadIdx.x);
  u32 nt  = (u32)(gridDim.x*blockDim.x);
  u32 nb_ = (u32)gridDim.x;
  u32 bc_round = 0;
  u32 m = (u32)E;
  int R = 0;

  // ---- round 0, phase B only: A0 complete, b0 seeded (prefix 1) ----
  for (u32 i = tid; i < m; i += nt){
    uint4 en = lde(A0 + i);
    u64 k = (1ull << 52) | ((u64)en.w << 20) | (u64)(0xFFFFFu - en.x);
    if (ldu64(b0 + en.y) == k && ldu64(b0 + en.z) == k){
      craw[en.z] = (int)en.y; medge[en.y] = (int)en.x;
    }
  }
  bc_round++; gbar(arrive, bc_round * nb_);

  // ---- grid phase: 1 pass + 1 barrier per round ----
  while (m > TAIL_M && R < MAX_ROUNDS){
    uint4* cur = (R & 1) ? A1 : A0;
    uint4* nxt = (R & 1) ? A0 : A1;
    u64*   cb  = (R & 1) ? b1 : b0;
    u64*   nb  = (R & 1) ? b0 : b1;
    if (tid == 0) stu32(cnt + ((R+2)&3), 0u);
    u32* cslot = cnt + ((R+1)&3);
    u64 kpfx = ((u64)(R+1)) << 52;
    pass_batched(cur, m, tid, nt, kpfx, cb, nb, rc, craw, medge, nxt, cslot);
    bc_round++; gbar(arrive, bc_round * nb_);
    R++;
    m = ldu32(cnt + (R & 3));
  }

  // ---- tail phase: single block, block barriers only ----
  if (blockIdx.x != 0) return;
  while (m != 0u && R < MAX_ROUNDS){
    uint4* cur = (R & 1) ? A1 : A0;
    uint4* nxt = (R & 1) ? A0 : A1;
    u64*   cb  = (R & 1) ? b1 : b0;
    u64*   nb  = (R & 1) ? b0 : b1;
    if (threadIdx.x == 0) stu32(cnt + ((R+2)&3), 0u);
    u32* cslot = cnt + ((R+1)&3);
    u64 kpfx = ((u64)(R+1)) << 52;
    __syncthreads();
    pass_batched(cur, m, (u32)threadIdx.x, (u32)blockDim.x, kpfx, cb, nb, rc,
                 craw, medge, nxt, cslot);
    asm volatile("s_waitcnt vmcnt(0) lgkmcnt(0)" ::: "memory");
    __syncthreads();
    R++;
    m = ldu32(cnt + (R & 3));
  }
}

__global__ void k_rootflag(const int* __restrict__ craw, u32* __restrict__ rf, int N){
  int i = blockIdx.x*blockDim.x + threadIdx.x;
  if (i < N) rf[i] = (craw[i] == i) ? 1u : 0u;
}

// ---------------- generic exclusive scan (n <= 65536) ----------------
__global__ void scan_p1(const u32* __restrict__ in, u32* __restrict__ out,
                        u32* __restrict__ bsums, const u32* __restrict__ nptr){
  __shared__ u32 sh[256];
  u32 n = *nptr;
  int t = threadIdx.x;
  u32 i = blockIdx.x*256u + (u32)t;
  u32 v = (i < n) ? in[i] : 0u;
  sh[t] = v; __syncthreads();
  for (int o = 1; o < 256; o <<= 1){
    u32 a = (t >= o) ? sh[t-o] : 0u;
    __syncthreads();
    sh[t] += a;
    __syncthreads();
  }
  if (i < n) out[i] = sh[t] - v;
  if (t == 255) bsums[blockIdx.x] = sh[255];
}
__global__ void scan_p2(u32* bsums, u32* total){
  __shared__ u32 sh[256];
  int t = threadIdx.x;
  u32 v = bsums[t];
  sh[t] = v; __syncthreads();
  for (int o = 1; o < 256; o <<= 1){
    u32 a = (t >= o) ? sh[t-o] : 0u;
    __syncthreads();
    sh[t] += a;
    __syncthreads();
  }
  bsums[t] = sh[t] - v;
  if (t == 255 && total) *total = sh[255];
}
__global__ void scan_p3(u32* out, const u32* __restrict__ bsums, const u32* __restrict__ nptr){
  u32 n = *nptr;
  u32 i = blockIdx.x*256u + threadIdx.x;
  if (i < n) out[i] += bsums[blockIdx.x];
}

// ---------------- final cluster ids (+ write cluster output) ----------------
__global__ void k_clusterout(const int* __restrict__ craw, const u32* __restrict__ newid,
                             int* __restrict__ clout, float* __restrict__ out,
                             size_t offC, int N){
  int i = blockIdx.x*blockDim.x + threadIdx.x;
  if (i < N){
    int cl = (int)newid[craw[i]];
    clout[i] = cl;
    out[offC + i] = (float)cl;
  }
}

__global__ void k_hist(const int* __restrict__ row, const int* __restrict__ clout,
                       u32* __restrict__ hist, int E){
  int i0 = blockIdx.x*blockDim.x + threadIdx.x;
  int nt = gridDim.x*blockDim.x;
  for (int e = i0; e < E; e += nt) atomicAdd(&hist[clout[row[e]]], 1u);
}

__global__ void k_scatter(const int* __restrict__ row, const int* __restrict__ col,
                          const int* __restrict__ clout, const u32* __restrict__ segoff,
                          u32* __restrict__ cur2, u32* __restrict__ ccbuf, int E){
  int i0 = blockIdx.x*blockDim.x + threadIdx.x;
  int nt = gridDim.x*blockDim.x;
  for (int e = i0; e < E; e += nt){
    int cr = clout[row[e]];
    u32 pos = segoff[cr] + atomicAdd(&cur2[cr], 1u);
    ccbuf[pos] = (u32)clout[col[e]];
  }
}

// ---------------- per-segment sort + dedup (1 wave / block) ----------------
__global__ void k_segsort(const u32* __restrict__ hdr, const u32* __restrict__ hist,
                          const u32* __restrict__ segoff, u32* __restrict__ ccbuf,
                          u32* __restrict__ uniqcnt){
  int c = (int)hdr[2];
  __shared__ u32 sh[1024];
  int lane = threadIdx.x;   // block = 64 threads
  for (int seg = blockIdx.x; seg < c; seg += gridDim.x){
    int n = (int)hist[seg];
    if (n <= 0){ if (lane == 0) uniqcnt[seg] = 0u; continue; }
    u32 off = segoff[seg];
    if (n <= 64){
      u32 v = (lane < n) ? ccbuf[off + lane] : 0xFFFFFFFFu;
      #pragma unroll
      for (int k = 2; k <= 64; k <<= 1)
        for (int j = k >> 1; j > 0; j >>= 1){
          u32 p = __shfl_xor(v, j);
          bool up  = ((lane & k) == 0);
          bool low = ((lane & j) == 0);
          u32 mn = v < p ? v : p, mx = v < p ? p : v;
          v = (up == low) ? mn : mx;
        }
      u32 pv = __shfl_up(v, 1);
      bool un = (lane < n) && (lane == 0 || v != pv);
      u64 bal = __ballot(un);
      int cnt = __popcll(bal);
      int rk  = __popcll(bal & ((1ull << lane) - 1ull));
      if (un) ccbuf[off + rk] = v;
      if (lane == 0) uniqcnt[seg] = (u32)cnt;
    } else {
      int nn = n > 1024 ? 1024 : n;
      for (int i = lane; i < nn; i += 64) sh[i] = ccbuf[off + i];
      __syncthreads();
      for (int p = 0; p < nn; p++){
        int st = p & 1;
        for (int i = lane; 2*i + 1 + st < nn; i += 64){
          int a = 2*i + st;
          u32 x0 = sh[a], x1 = sh[a+1];
          if (x0 > x1){ sh[a] = x1; sh[a+1] = x0; }
        }
        __syncthreads();
      }
      if (lane == 0){
        int cnt = 0; u32 prev = 0u;
        for (int i = 0; i < nn; i++){
          u32 xv = sh[i];
          if (i == 0 || xv != prev){ ccbuf[off + cnt] = xv; cnt++; prev = xv; }
        }
        uniqcnt[seg] = (u32)cnt;
      }
      __syncthreads();
    }
  }
}

// ---------------- write new_edge_index ----------------
__global__ void k_writeedges(const u32* __restrict__ hdr, const u32* __restrict__ segoff,
                             const u32* __restrict__ uniqcnt, const u32* __restrict__ uniqoff,
                             const u32* __restrict__ ccbuf, float* __restrict__ out){
  int c = (int)hdr[2]; u32 Ep = hdr[3];
  size_t base = (size_t)c * CH_;
  int gw   = (blockIdx.x*blockDim.x + threadIdx.x) >> 6;
  int lane = threadIdx.x & 63;
  int nw   = (gridDim.x*blockDim.x) >> 6;
  for (int seg = gw; seg < c; seg += nw){
    int cnt = (int)uniqcnt[seg];
    u32 so = segoff[seg], uo = uniqoff[seg];
    for (int j = lane; j < cnt; j += 64){
      u32 cc = ccbuf[so + j];
      out[base + uo + j]              = (float)seg;
      out[base + (size_t)Ep + uo + j] = (float)cc;
    }
  }
}

// ---------------- new_x / new_batch / new_edge_score (wave per root) ----------------
__global__ void k_final(const u32* __restrict__ hdr, const int* __restrict__ craw,
                        const u32* __restrict__ newid, const int* __restrict__ medge,
                        const int* __restrict__ row, const int* __restrict__ col,
                        const float* __restrict__ score, const int* __restrict__ batch,
                        const float* __restrict__ x, float* __restrict__ out, int N){
  int c = (int)hdr[2]; u32 Ep = hdr[3];
  size_t offB = (size_t)c * CH_ + 2ull * (size_t)Ep;
  size_t offS = offB + (size_t)c;
  int gw   = (blockIdx.x*blockDim.x + threadIdx.x) >> 6;
  int lane = threadIdx.x & 63;
  int nw   = (gridDim.x*blockDim.x) >> 6;
  for (int i = gw; i < N; i += nw){
    if (craw[i] != i) continue;
    int j = (int)newid[i];
    int e = medge[i];
    int lo = i, hi = i; float sc = 1.0f;
    if (e >= 0){
      int r = row[e], cc = col[e];
      lo = min(r, cc); hi = max(r, cc);
      sc = score[e];
    }
    float v0 = x[(size_t)lo*CH_ + lane];
    float v1 = x[(size_t)lo*CH_ + 64 + lane];
    if (hi != lo){ v0 += x[(size_t)hi*CH_ + lane]; v1 += x[(size_t)hi*CH_ + 64 + lane]; }
    out[(size_t)j*CH_ + lane]      = v0 * sc;
    out[(size_t)j*CH_ + 64 + lane] = v1 * sc;
    if (lane == 0){
      out[offB + j] = (float)batch[hi];  // CPU-XLA scatter: last (max-index) member wins
      out[offS + j] = sc;
    }
  }
}

extern "C" void kernel_launch(void* const* d_in, const int* in_sizes, int n_in,
                              void* d_out, int out_size, void* d_ws, size_t ws_size,
                              hipStream_t stream) {
  const float* x     = (const float*)d_in[0];
  const int*   eidx  = (const int*)d_in[1];
  const int*   batch = (const int*)d_in[2];
  const float* lw    = (const float*)d_in[3];
  const float* lb    = (const float*)d_in[4];

  int N = in_sizes[0] / CH_;
  int E = in_sizes[1] / 2;
  const int* row = eidx;
  const int* col = eidx + E;
  float* out = (float*)d_out;

  // ---- workspace carve ----
  char* w = (char*)d_ws;
  size_t off = 0;
  auto carve = [&](size_t bytes) -> void* {
    void* p = w + off;
    off += (bytes + 255) & ~(size_t)255;
    return p;
  };
  u32*    hdr    = (u32*)   carve(256);
  double* den    = (double*)carve((size_t)N*8);
  u64*    b0     = (u64*)   carve((size_t)N*8);
  u64*    b1     = (u64*)   carve((size_t)N*8);
  float*  s      = (float*) carve((size_t)N*4);
  float*  t      = (float*) carve((size_t)N*4);
  float*  rawex  = (float*) carve((size_t)E*4);   // becomes score
  u32*    mxbits = (u32*)   carve((size_t)N*4);
  int*    craw   = (int*)   carve((size_t)N*4);
  u32*    rf     = (u32*)   carve((size_t)N*4);
  u32*    newid  = (u32*)   carve((size_t)N*4);
  int*    medge  = (int*)   carve((size_t)N*4);
  int*    clout  = (int*)   carve((size_t)N*4);
  u32*    rc     = (u32*)   carve((size_t)E*4);
  uint4*  A0     = (uint4*) carve((size_t)E*16);
  uint4*  A1     = (uint4*) carve((size_t)E*16);
  u32*    bsums  = (u32*)   carve(256*4);
  // alias post-match scratch into the (then-dead) A0 region
  char* a = (char*)A0;
  size_t aoff = 0;
  auto acarve = [&](size_t bytes) -> void* {
    void* p = a + aoff;
    aoff += (bytes + 255) & ~(size_t)255;
    return p;
  };
  u32* ccbuf   = (u32*)acarve((size_t)E*4);
  u32* hist    = (u32*)acarve((size_t)(N+64)*4);
  u32* segoff  = (u32*)acarve((size_t)(N+64)*4);
  u32* cur2    = (u32*)acarve((size_t)(N+64)*4);
  u32* uniqcnt = (u32*)acarve((size_t)(N+64)*4);
  u32* uniqoff = (u32*)acarve((size_t)(N+64)*4);
  (void)ws_size; (void)n_in;

  int nbE = (E + 255) / 256;
  int nbN = (N + 255) / 256;

  k_init<<<512, 256, 0, stream>>>(hdr, mxbits, den, b0, b1, craw, medge, N);
  k_dots<<<(N + 3)/4, 256, 0, stream>>>(x, lw, s, t, N);
  k_rawmax<<<nbE, 256, 0, stream>>>(s, t, row, col, lb, rawex, mxbits, E);
  k_exden<<<nbE, 256, 0, stream>>>(col, mxbits, rawex, den, E);
  k_scorekey<<<nbE, 256, 0, stream>>>(row, col, rawex, den, rc, A0, b0, E);

  {
    // cooperative launch solely for the co-residency guarantee (128 <= 256 CUs);
    // synchronization inside is the custom fence-free barrier.
    void* kargs[] = { &hdr, (void*)&rc, &b0, &b1, &craw, &medge, &A0, &A1, &E };
    hipLaunchCooperativeKernel((void*)k_match, dim3(NBLK), dim3(1024), kargs, 0, stream);
  }

  k_rootflag<<<nbN, 256, 0, stream>>>(craw, rf, N);

  // scan rootflag -> newid ; total -> hdr[2] (= c). n from hdr[6] (= N)
  scan_p1<<<256, 256, 0, stream>>>(rf, newid, bsums, &hdr[6]);
  scan_p2<<<1, 256, 0, stream>>>(bsums, &hdr[2]);
  scan_p3<<<256, 256, 0, stream>>>(newid, bsums, &hdr[6]);

  k_clusterout<<<nbN, 256, 0, stream>>>(craw, newid, clout, out, (size_t)(out_size - N), N);
  k_init2<<<(N + 64 + 255)/256, 256, 0, stream>>>(hist, cur2, uniqcnt, N + 64);
  k_hist<<<nbE, 256, 0, stream>>>(row, clout, hist, E);

  // scan hist -> segoff ; n from hdr[2] (= c)
  scan_p1<<<256, 256, 0, stream>>>(hist, segoff, bsums, &hdr[2]);
  scan_p2<<<1, 256, 0, stream>>>(bsums, &hdr[4]);
  scan_p3<<<256, 256, 0, stream>>>(segoff, bsums, &hdr[2]);

  k_scatter<<<nbE, 256, 0, stream>>>(row, col, clout, segoff, cur2, ccbuf, E);
  k_segsort<<<4096, 64, 0, stream>>>(hdr, hist, segoff, ccbuf, uniqcnt);

  // scan uniqcnt -> uniqoff ; total -> hdr[3] (= E')
  scan_p1<<<256, 256, 0, stream>>>(uniqcnt, uniqoff, bsums, &hdr[2]);
  scan_p2<<<1, 256, 0, stream>>>(bsums, &hdr[3]);
  scan_p3<<<256, 256, 0, stream>>>(uniqoff, bsums, &hdr[2]);

  k_writeedges<<<2048, 256, 0, stream>>>(hdr, segoff, uniqcnt, uniqoff, ccbuf, out);
  k_final<<<4096, 256, 0, stream>>>(hdr, craw, newid, medge, row, col, rawex, batch, x, out, N);
}